// Round 6
// baseline (4589.427 us; speedup 1.0000x reference)
//
#include <hip/hip_runtime.h>
#include <hip/hip_bf16.h>
#include <math.h>

// ---------------------------------------------------------------------------
// UBLSTMP: bidirectional LSTM-with-projection.
//   fwd: T=512 sequential steps, batch 32, H=1024, P=512
//   bwd: 32 sequential steps over blocks of 32, batch 512, H=1024, P=512
// Round-6: flag-free forward scan, done right this time.
//   - h_hist pre-poisoned 0xFF per launch (u64==~0 == 4x bf16 NaN, h finite
//     => unreachable). Consumers poll the h DATA with batched, branch-free
//     relaxed agent 8B atomic loads (one LLC RT per poll round); producers
//     publish granules directly from consumer threads with relaxed atomic
//     stores. No flags, no vmcnt drains, no publish barrier for fwd.
//   - 128 fwd blocks x 8 units (weights in VGPRs) as round 5.
//   - bwd scan (off critical path) unchanged from round 5.
// ---------------------------------------------------------------------------

typedef __bf16 bf16_t;
typedef __bf16 bf16x8 __attribute__((ext_vector_type(8)));
typedef float f32x4 __attribute__((ext_vector_type(4)));
typedef unsigned int uint32;
typedef unsigned long long u64;

#define DEV __device__ __forceinline__

DEV bf16x8 ldg8(const bf16_t* p) { return *reinterpret_cast<const bf16x8*>(p); }
DEV u64 ld_a64(const u64* p) {
  return __hip_atomic_load(p, __ATOMIC_RELAXED, __HIP_MEMORY_SCOPE_AGENT);
}
DEV void st_a64(u64* p, u64 v) {
  __hip_atomic_store(p, v, __ATOMIC_RELAXED, __HIP_MEMORY_SCOPE_AGENT);
}
DEV bf16x8 ld_llc8(const bf16_t* p) {
  union { bf16x8 v; u64 q[2]; } u;
  u64* pp = (u64*)p;
  u.q[0] = ld_a64(pp); u.q[1] = ld_a64(pp + 1);
  return u.v;
}
DEV void st_llc_u32(uint32* p, uint32 v) {
  __hip_atomic_store(p, v, __ATOMIC_RELAXED, __HIP_MEMORY_SCOPE_AGENT);
}
DEV f32x4 mfma16(bf16x8 a, bf16x8 b, f32x4 c) {
  return __builtin_amdgcn_mfma_f32_16x16x32_bf16(a, b, c, 0, 0, 0);
}
DEV float sigmoidf_(float x) { return 1.0f / (1.0f + __expf(-x)); }
DEV float tanhf_(float x) {  // fast tanh via e^{2x}
  float e = __expf(2.0f * x);
  return (e - 1.0f) / (e + 1.0f);
}
DEV unsigned short bfbits(float x) {
  union { __bf16 b; unsigned short s; } u; u.b = (bf16_t)x; return u.s;
}

struct Params {
  const float* data;    // [32,512,240]
  const float* mask;    // [32,512]
  const float* wx_f; const float* wr_f; const float* bias_f; const float* wp_f;
  const float* wx_b; const float* wr_b; const float* bias_b; const float* wp_b;
  float* out;           // [32,512,1024]
  bf16_t* data_bf;      // [32,512,256] (K padded 240->256 with zeros)
  bf16_t* Wf;           // [4096,1280] packed fwd rows: [0,1024)=Wc, [1024,1280)=Wx
  bf16_t* Wb;           // [4096,768]  packed bwd rows: [0,512)=Wr, [512,768)=Wx
  bf16_t* wrf;          // [4096,512] bf16 copy of wr_f
  bf16_t* wpT;          // [1024,512] wp_f transposed
  bf16_t* wpf;          // [512,1024]
  bf16_t* wpb;          // [512,1024]
  float* bias_f_p;      // [4096] packed
  float* bias_b_p;      // [4096] packed
  bf16_t* h_hist;       // [512,32,1024] fwd h history; canary 0xFF per launch
  bf16_t* h_buf;        // [512,1024]     bwd h (write-through)
  bf16_t* r_buf;        // [512,512]      bwd r (write-through)
  f32x4*  chb;          // [512,512] private (c0,h0,c1,h1) per unit-pair
  int* bcA;             // [128 slots x 16]
  int* bcC;             // [128 slots x 16]
};

// ---------------- sync helpers (bwd only) ----------------
DEV void poll_ge(int* p, int tgt) {
  while (__hip_atomic_load(p, __ATOMIC_RELAXED, __HIP_MEMORY_SCOPE_AGENT) < tgt)
    __builtin_amdgcn_s_sleep(1);
}
DEV void st_slot(int* p, int v) {
  __hip_atomic_store(p, v, __ATOMIC_RELAXED, __HIP_MEMORY_SCOPE_AGENT);
}
DEV void drain_sync() {
  asm volatile("s_waitcnt vmcnt(0)" ::: "memory");
  __syncthreads();
}

// ---------------- prep kernels ----------------
__global__ void k_data(Params P) {
  int idx = blockIdx.x * 256 + threadIdx.x;   // 32*512*256
  int k = idx & 255; int row = idx >> 8;
  float v = (k < 240) ? P.data[(size_t)row * 240 + k] : 0.0f;
  P.data_bf[idx] = (bf16_t)v;
}

__global__ void k_prep_w(Params P) {
  int idx = blockIdx.x * 256 + threadIdx.x;
  int n = 4096 * 512;
  if (idx < n) { P.wrf[idx] = (bf16_t)P.wr_f[idx]; return; }
  idx -= n; n = 1024 * 512;
  if (idx < n) { int h = idx >> 9, p = idx & 511;
                 P.wpT[idx] = (bf16_t)P.wp_f[(size_t)p * 1024 + h]; return; }
  idx -= n; n = 512 * 1024;
  if (idx < n) { P.wpf[idx] = (bf16_t)P.wp_f[idx]; return; }
  idx -= n; n = 512 * 1024;
  if (idx < n) { P.wpb[idx] = (bf16_t)P.wp_b[idx]; return; }
}

// fwd packed rows: pr = j*32 + grp*8 + uu  <->  global gate row grp*1024 + j*8 + uu
__global__ void k_packf(Params P) {
  int pr = blockIdx.x, k = threadIdx.x;     // k in [0,256)
  int jj = pr >> 5, lr = pr & 31, grp = lr >> 3, uu = lr & 7;
  int grow = grp * 1024 + jj * 8 + uu;
  float v = (k < 240) ? P.wx_f[(size_t)grow * 240 + k] : 0.0f;
  P.Wf[(size_t)pr * 1280 + 1024 + k] = (bf16_t)v;
  if (k == 0) P.bias_f_p[pr] = P.bias_f[grow];
}

// bwd packed rows: pr = ut*256 + grp*64 + uu <-> global row grp*1024 + ut*64 + uu
__global__ void k_packb(Params P) {
  int pr = blockIdx.x; int k = blockIdx.y * 256 + threadIdx.x;  // k in [0,768)
  int ut = pr >> 8, rem = pr & 255, grp = rem >> 6, uu = rem & 63;
  int grow = grp * 1024 + ut * 64 + uu;
  float v;
  if (k < 512) v = P.wr_b[(size_t)grow * 512 + k];
  else { int kx = k - 512; v = (kx < 240) ? P.wx_b[(size_t)grow * 240 + kx] : 0.0f; }
  P.Wb[(size_t)pr * 768 + k] = (bf16_t)v;
  if (k == 0) P.bias_b_p[pr] = P.bias_b[grow];
}

// Wc = wr_f @ wp_f : [4096,1024], K=512; into packed Wf rows, cols [0,1024)
__global__ void wc_gemm(Params P) {
  int tid = threadIdx.x, lane = tid & 63, wave = tid >> 6;
  int lane15 = lane & 15, laneh = lane >> 4;
  int mt = blockIdx.x >> 4, nt = blockIdx.x & 15;
  f32x4 acc[4] = {};
  for (int kc = 0; kc < 16; ++kc) {
    int kl = kc * 32 + laneh * 8;
    bf16x8 bv = ldg8(P.wpT + (size_t)(nt * 64 + wave * 16 + lane15) * 512 + kl);
#pragma unroll
    for (int mh = 0; mh < 4; ++mh) {
      bf16x8 av = ldg8(P.wrf + (size_t)(mt * 64 + mh * 16 + lane15) * 512 + kl);
      acc[mh] = mfma16(av, bv, acc[mh]);
    }
  }
#pragma unroll
  for (int mh = 0; mh < 4; ++mh)
#pragma unroll
    for (int q = 0; q < 4; ++q) {
      int m = mt * 64 + mh * 16 + laneh * 4 + q;
      int grp = m >> 10, unit = m & 1023, jj = unit >> 3, u8 = unit & 7;
      int pr = jj * 32 + grp * 8 + u8;
      int ncol = nt * 64 + wave * 16 + lane15;
      P.Wf[(size_t)pr * 1280 + ncol] = (bf16_t)acc[mh][q];
    }
}

// ---------------- the scan kernel: blocks 0..127 fwd, 128..255 bwd ----------
__global__ void __launch_bounds__(256, 1) scan_kernel(Params P) {
  __shared__ union SM {
    float red[4][2][2][16][17];   // fwd: [wave][m][nh][m16][n16 pad]
    float gates[4][64][64];       // bwd: [group][n][uu]
  } sm;
  const int tid = threadIdx.x;
  const int lane = tid & 63, wave = tid >> 6;
  const int lane15 = lane & 15, laneh = lane >> 4;

  if (blockIdx.x < 128) {
    // =============== forward scan: block j owns hidden units j*8..j*8+7 ====
    const int j = blockIdx.x;
    const bf16_t* Wfp = P.Wf + (size_t)(j * 32) * 1280;
    // weights in VGPRs: wave w covers h-K [w*256,+256) and x-K [w*64,+64)
    bf16x8 wh[2][8], wx[2][2];
#pragma unroll
    for (int nh = 0; nh < 2; ++nh) {
#pragma unroll
      for (int kc = 0; kc < 8; ++kc)
        wh[nh][kc] = ldg8(Wfp + (size_t)(nh * 16 + lane15) * 1280 +
                          wave * 256 + kc * 32 + laneh * 8);
#pragma unroll
      for (int kc = 0; kc < 2; ++kc)
        wx[nh][kc] = ldg8(Wfp + (size_t)(nh * 16 + lane15) * 1280 +
                          1024 + wave * 64 + kc * 32 + laneh * 8);
    }
    const int cb = tid >> 2, up = tid & 3;   // consumer: (batch, unit-pair)
    float biasr[2][4];
    if (tid < 128) {
#pragma unroll
      for (int e = 0; e < 2; ++e)
#pragma unroll
        for (int g = 0; g < 4; ++g)
          biasr[e][g] = P.bias_f_p[j * 32 + g * 8 + 2 * up + e];
    }
    float c_st[2] = {0.f, 0.f}, h_st[2] = {0.f, 0.f};

    for (int t = 0; t < 512; ++t) {
      // ---- x-side GEMM first (no dependence on previous step) ----
      f32x4 acc[2][2] = {};
      {
        bf16x8 ax[2][2];
#pragma unroll
        for (int kc = 0; kc < 2; ++kc) {
          int kx = wave * 64 + kc * 32 + laneh * 8;
          ax[0][kc] = ldg8(P.data_bf + ((size_t)(lane15 * 512 + t)) * 256 + kx);
          ax[1][kc] = ldg8(P.data_bf + ((size_t)((16 + lane15) * 512 + t)) * 256 + kx);
        }
#pragma unroll
        for (int kc = 0; kc < 2; ++kc)
#pragma unroll
          for (int m = 0; m < 2; ++m) {
            acc[m][0] = mfma16(ax[m][kc], wx[0][kc], acc[m][0]);
            acc[m][1] = mfma16(ax[m][kc], wx[1][kc], acc[m][1]);
          }
      }
      // ---- acquire h(t-1): batched branch-free canary poll on the DATA ----
      if (t > 0) {
        const bf16_t* hrow = P.h_hist + (size_t)(t - 1) * 32768;
        union QU { u64 q[2]; bf16x8 v; } qa[2][8];
        for (;;) {
          bool ok = true;
#pragma unroll
          for (int m = 0; m < 2; ++m)
#pragma unroll
            for (int kc = 0; kc < 8; ++kc) {
              u64* p = (u64*)(hrow + (size_t)(m * 16 + lane15) * 1024 +
                              wave * 256 + kc * 32 + laneh * 8);
              qa[m][kc].q[0] = ld_a64(p);
              qa[m][kc].q[1] = ld_a64(p + 1);
            }
#pragma unroll
          for (int m = 0; m < 2; ++m)
#pragma unroll
            for (int kc = 0; kc < 8; ++kc)
              ok = ok & (qa[m][kc].q[0] != ~0ull) & (qa[m][kc].q[1] != ~0ull);
          if (__builtin_expect(ok, 1)) break;
          __builtin_amdgcn_s_sleep(1);
        }
#pragma unroll
        for (int kc = 0; kc < 8; ++kc)
#pragma unroll
          for (int m = 0; m < 2; ++m) {
            acc[m][0] = mfma16(qa[m][kc].v, wh[0][kc], acc[m][0]);
            acc[m][1] = mfma16(qa[m][kc].v, wh[1][kc], acc[m][1]);
          }
      }
      // ---- cross-wave reduce via LDS ----
      __syncthreads();   // prev iteration's consumer reads of sm.red are done
#pragma unroll
      for (int m = 0; m < 2; ++m)
#pragma unroll
        for (int nh = 0; nh < 2; ++nh)
#pragma unroll
          for (int q = 0; q < 4; ++q)
            sm.red[wave][m][nh][laneh * 4 + q][lane15] = acc[m][nh][q];
      __syncthreads();

      // ---- consumer: 128 threads, 2 cells each; publish granules direct ----
      if (tid < 128) {
        float mk = P.mask[cb * 512 + t];
        uint32 pk = 0;
#pragma unroll
        for (int e = 0; e < 2; ++e) {
          float g4[4];
#pragma unroll
          for (int g = 0; g < 4; ++g) {
            int lr = g * 8 + 2 * up + e;
            float v = biasr[e][g];
#pragma unroll
            for (int w2 = 0; w2 < 4; ++w2)
              v += sm.red[w2][cb >> 4][lr >> 4][cb & 15][lr & 15];
            g4[g] = v;
          }
          float iv = sigmoidf_(g4[0]);
          float fv = sigmoidf_(g4[1]);
          float gv = tanhf_(g4[2]);
          float ov = sigmoidf_(g4[3]);
          float cnew = fminf(1.0f, fmaxf(-1.0f, fv * c_st[e] + iv * gv));
          float hnew = ov * tanhf_(cnew);
          c_st[e] = mk * cnew + (1.0f - mk) * c_st[e];
          h_st[e] = mk * hnew + (1.0f - mk) * h_st[e];
          pk |= ((uint32)bfbits(h_st[e])) << (16 * e);
        }
        uint32 po = __shfl_xor((int)pk, 1);    // partner unit-pair
        if (!(up & 1)) {
          u64 qq = (u64)pk | ((u64)po << 32);  // units 2up..2up+3
          st_a64((u64*)(P.h_hist + (size_t)t * 32768 + cb * 1024 + j * 8 + 2 * up), qq);
        }
      }
      // no trailing barrier: next loop's pre-write barrier protects sm.red
    }
  } else {
    // =============== backward scan (blocked, batch 512, 32 steps) ==========
    const int bx = blockIdx.x - 128;
    const int btA = bx >> 4, utA = bx & 15;   // phase A: [64 batch] x [64 units]
    const int btC = bx >> 3, ptC = bx & 7;    // phase C: [32 batch] x [64 p]
    const int un = tid & 31, nr = tid >> 5;   // phase-A consumer mapping
    float biasB[2][4];
#pragma unroll
    for (int e = 0; e < 2; ++e)
#pragma unroll
      for (int g = 0; g < 4; ++g)
        biasB[e][g] = P.bias_b_p[utA * 256 + g * 64 + 2 * un + e];

    for (int s = 0; s < 32; ++s) {
      // ---- phase A: gates + state update, writes h_buf (write-through) ----
      if (s > 0) {
        if (tid < 16) {
          int bxp = (btA * 2 + (tid >> 3)) * 8 + (tid & 7);
          poll_ge(P.bcC + bxp * 16, s);
        }
        __syncthreads();
        asm volatile("" ::: "memory");
      } else {
        __syncthreads();
      }
      f32x4 acc[4][4] = {};
      const bf16_t* WbBase = P.Wb + (size_t)(utA * 256 + wave * 64) * 768;
      for (int kc = 0; kc < 24; ++kc) {
        int kb = kc * 32;
        if (kb < 512 && s == 0) continue;    // r_{-1} = 0
        int kl = kb + laneh * 8;
        bf16x8 av[4];
        if (kb < 512) {
#pragma unroll
          for (int mh = 0; mh < 4; ++mh)
            av[mh] = ld_llc8(P.r_buf + (size_t)(btA * 64 + mh * 16 + lane15) * 512 + kl);
        } else {
          int kx = kl - 512;
#pragma unroll
          for (int mh = 0; mh < 4; ++mh) {
            int n = btA * 64 + mh * 16 + lane15;
            int t2 = (n & 15) * 32 + 31 - s;
            av[mh] = ldg8(P.data_bf + ((size_t)((n >> 4) * 512 + t2)) * 256 + kx);
          }
        }
#pragma unroll
        for (int nf = 0; nf < 4; ++nf) {
          bf16x8 bv = ldg8(WbBase + (size_t)(nf * 16 + lane15) * 768 + kl);
#pragma unroll
          for (int mh = 0; mh < 4; ++mh)
            acc[mh][nf] = mfma16(av[mh], bv, acc[mh][nf]);
        }
      }
#pragma unroll
      for (int mh = 0; mh < 4; ++mh)
#pragma unroll
        for (int nf = 0; nf < 4; ++nf)
#pragma unroll
          for (int q = 0; q < 4; ++q)
            sm.gates[wave][mh * 16 + laneh * 4 + q][nf * 16 + lane15] = acc[mh][nf][q];
      __syncthreads();

      for (int ii = 0; ii < 8; ++ii) {
        int n = ii * 8 + nr;
        int ng = btA * 64 + n;
        int b = ng >> 4;
        int t2 = (ng & 15) * 32 + 31 - s;
        float mk = P.mask[b * 512 + t2];
        size_t cix = (size_t)ng * 512 + utA * 32 + un;  // unit-pair index
        f32x4 chv;
        if (s == 0) { chv[0] = 0.f; chv[1] = 0.f; chv[2] = 0.f; chv[3] = 0.f; }
        else chv = P.chb[cix];
        uint32 pk = 0;
#pragma unroll
        for (int e = 0; e < 2; ++e) {
          float gi = sm.gates[0][n][2 * un + e] + biasB[e][0];
          float gf = sm.gates[1][n][2 * un + e] + biasB[e][1];
          float gg = sm.gates[2][n][2 * un + e] + biasB[e][2];
          float go = sm.gates[3][n][2 * un + e] + biasB[e][3];
          float iv = sigmoidf_(gi), fv = sigmoidf_(gf);
          float gv = tanhf_(gg), ov = sigmoidf_(go);
          float cold = chv[2 * e], hold = chv[2 * e + 1];
          float cnew = fminf(1.0f, fmaxf(-1.0f, fv * cold + iv * gv));
          float hnew = ov * tanhf_(cnew);
          float cm = mk * cnew + (1.0f - mk) * cold;
          float hm = mk * hnew + (1.0f - mk) * hold;
          chv[2 * e] = cm; chv[2 * e + 1] = hm;
          pk |= ((uint32)bfbits(hm)) << (16 * e);
        }
        P.chb[cix] = chv;
        st_llc_u32((uint32*)(P.h_buf + (size_t)ng * 1024 + utA * 64 + 2 * un), pk);
      }
      drain_sync();
      if (tid == 0) st_slot(&P.bcA[bx * 16], s + 1);

      // ---- phase C: r = h @ wp_b.T ; write d_out and r_buf ----
      if (tid < 16) poll_ge(P.bcA + ((btC >> 1) * 16 + tid) * 16, s + 1);
      __syncthreads();
      asm volatile("" ::: "memory");
      f32x4 acc2[2] = {};
      for (int kc = 0; kc < 32; ++kc) {
        int kl = kc * 32 + laneh * 8;
        bf16x8 bv = ldg8(P.wpb + (size_t)(ptC * 64 + wave * 16 + lane15) * 1024 + kl);
        bf16x8 a0 = ld_llc8(P.h_buf + (size_t)(btC * 32 + lane15) * 1024 + kl);
        bf16x8 a1 = ld_llc8(P.h_buf + (size_t)(btC * 32 + 16 + lane15) * 1024 + kl);
        acc2[0] = mfma16(a0, bv, acc2[0]);
        acc2[1] = mfma16(a1, bv, acc2[1]);
      }
#pragma unroll
      for (int mh = 0; mh < 2; ++mh)
#pragma unroll
        for (int q = 0; q < 4; ++q) {
          int nl = mh * 16 + laneh * 4 + q;
          int ng = btC * 32 + nl;
          int b = ng >> 4;
          int t2 = (ng & 15) * 32 + 31 - s;
          int p = ptC * 64 + wave * 16 + lane15;
          float v = acc2[mh][q];
          P.out[((size_t)b * 512 + t2) * 1024 + 512 + p] = v;
          float v2 = __shfl_xor(v, 1);
          if (!(lane & 1)) {
            uint32 pk = ((uint32)bfbits(v2) << 16) | bfbits(v);
            st_llc_u32((uint32*)(P.r_buf + (size_t)ng * 512 + p), pk);
          }
        }
      drain_sync();
      if (tid == 0) st_slot(&P.bcC[bx * 16], s + 1);
    }
  }
}

// out_f = h_hist @ wp_f.T : M=16384, N=512, K=1024
__global__ void fwd_proj(Params P) {
  int tid = threadIdx.x, lane = tid & 63, wave = tid >> 6;
  int lane15 = lane & 15, laneh = lane >> 4;
  int mt = blockIdx.x >> 3, nt = blockIdx.x & 7;
  f32x4 acc[4] = {};
  for (int kc = 0; kc < 32; ++kc) {
    int kl = kc * 32 + laneh * 8;
    bf16x8 bv = ldg8(P.wpf + (size_t)(nt * 64 + wave * 16 + lane15) * 1024 + kl);
#pragma unroll
    for (int mh = 0; mh < 4; ++mh) {
      bf16x8 av = ldg8(P.h_hist + (size_t)(mt * 64 + mh * 16 + lane15) * 1024 + kl);
      acc[mh] = mfma16(av, bv, acc[mh]);
    }
  }
#pragma unroll
  for (int mh = 0; mh < 4; ++mh)
#pragma unroll
    for (int q = 0; q < 4; ++q) {
      int m = mt * 64 + mh * 16 + laneh * 4 + q;
      int t = m >> 5, nb = m & 31;
      int p = nt * 64 + wave * 16 + lane15;
      P.out[((size_t)nb * 512 + t) * 1024 + p] = acc[mh][q];
    }
}

// ---------------------------------------------------------------------------
extern "C" void kernel_launch(void* const* d_in, const int* in_sizes, int n_in,
                              void* d_out, int out_size, void* d_ws, size_t ws_size,
                              hipStream_t stream) {
  (void)in_sizes; (void)n_in; (void)out_size; (void)ws_size;
  Params P;
  P.data   = (const float*)d_in[0];
  P.mask   = (const float*)d_in[1];
  P.wx_f   = (const float*)d_in[2];
  P.wr_f   = (const float*)d_in[3];
  P.bias_f = (const float*)d_in[4];
  P.wp_f   = (const float*)d_in[5];
  P.wx_b   = (const float*)d_in[6];
  P.wr_b   = (const float*)d_in[7];
  P.bias_b = (const float*)d_in[8];
  P.wp_b   = (const float*)d_in[9];
  P.out    = (float*)d_out;

  char* ws = (char*)d_ws;
  size_t o = 0;
  auto take = [&](size_t bytes) -> char* {
    char* p = ws + o; o += (bytes + 255) & ~(size_t)255; return p;
  };
  P.data_bf  = (bf16_t*)take(32ull * 512 * 256 * 2);
  P.Wf       = (bf16_t*)take(4096ull * 1280 * 2);
  P.Wb       = (bf16_t*)take(4096ull * 768 * 2);
  P.wrf      = (bf16_t*)take(4096ull * 512 * 2);
  P.wpT      = (bf16_t*)take(1024ull * 512 * 2);
  P.wpf      = (bf16_t*)take(512ull * 1024 * 2);
  P.wpb      = (bf16_t*)take(512ull * 1024 * 2);
  P.bias_f_p = (float*)take(4096 * 4);
  P.bias_b_p = (float*)take(4096 * 4);
  P.h_hist   = (bf16_t*)take(512ull * 32 * 1024 * 2);
  P.h_buf    = (bf16_t*)take(512ull * 1024 * 2);
  P.r_buf    = (bf16_t*)take(512ull * 512 * 2);
  P.chb      = (f32x4*)take(512ull * 512 * 16);
  size_t slot_i = 128ull * 16;
  char* cnts = take(2 * slot_i * 4);
  P.bcA  = (int*)cnts;
  P.bcC  = (int*)(cnts + slot_i * 4);

  hipMemsetAsync(cnts, 0, 2 * slot_i * 4, stream);
  // canary-fill h_hist: every u64 becomes ~0 (4x bf16 NaN — unreachable for
  // finite h). MUST be inside the graph: replays re-poison before each scan.
  hipMemsetAsync(P.h_hist, 0xFF, 512ull * 32 * 1024 * 2, stream);
  k_data<<<16384, 256, 0, stream>>>(P);
  k_prep_w<<<14336, 256, 0, stream>>>(P);
  k_packf<<<4096, 256, 0, stream>>>(P);
  k_packb<<<dim3(4096, 3), 256, 0, stream>>>(P);
  wc_gemm<<<1024, 256, 0, stream>>>(P);
  scan_kernel<<<256, 256, 0, stream>>>(P);
  fwd_proj<<<2048, 256, 0, stream>>>(P);
}

// Round 7
// 4302.965 us; speedup vs baseline: 1.0666x; 1.0666x over previous
//
#include <hip/hip_runtime.h>
#include <hip/hip_bf16.h>
#include <math.h>

// ---------------------------------------------------------------------------
// UBLSTMP: bidirectional LSTM-with-projection.
//   fwd: T=512 sequential steps, batch 32, H=1024, P=512
//   bwd: 32 sequential steps over blocks of 32, batch 512, H=1024, P=512
// Round-7: r5 sync protocol (flags + relaxed stores + drain) kept verbatim;
//   fwd per-block compute restructured to wave-autonomous full-K tiles:
//   wave = (batch-half, unit-half), M=16 x N=16(4 units x 4 gates) x K=1280,
//   40 MFMA into 4 acc chains. NO LDS in the fwd loop: gate gather via
//   12 shfls, activations in all 256 threads, h packed to 8B granules via
//   8 shfls and stored sc1 directly. One barrier + drain per step.
// ---------------------------------------------------------------------------

typedef __bf16 bf16_t;
typedef __bf16 bf16x8 __attribute__((ext_vector_type(8)));
typedef float f32x4 __attribute__((ext_vector_type(4)));
typedef unsigned int uint32;
typedef unsigned long long u64;

#define DEV __device__ __forceinline__

DEV bf16x8 ldg8(const bf16_t* p) { return *reinterpret_cast<const bf16x8*>(p); }
DEV u64 ld_a64(const u64* p) {
  return __hip_atomic_load(p, __ATOMIC_RELAXED, __HIP_MEMORY_SCOPE_AGENT);
}
DEV void st_a64(u64* p, u64 v) {
  __hip_atomic_store(p, v, __ATOMIC_RELAXED, __HIP_MEMORY_SCOPE_AGENT);
}
DEV bf16x8 ld_llc8(const bf16_t* p) {
  union { bf16x8 v; u64 q[2]; } u;
  u64* pp = (u64*)p;
  u.q[0] = ld_a64(pp); u.q[1] = ld_a64(pp + 1);
  return u.v;
}
DEV void st_llc_u32(uint32* p, uint32 v) {
  __hip_atomic_store(p, v, __ATOMIC_RELAXED, __HIP_MEMORY_SCOPE_AGENT);
}
DEV f32x4 mfma16(bf16x8 a, bf16x8 b, f32x4 c) {
  return __builtin_amdgcn_mfma_f32_16x16x32_bf16(a, b, c, 0, 0, 0);
}
DEV float sigmoidf_(float x) { return 1.0f / (1.0f + __expf(-x)); }
DEV float tanhf_(float x) {  // fast tanh via e^{2x}
  float e = __expf(2.0f * x);
  return (e - 1.0f) / (e + 1.0f);
}
DEV unsigned short bfbits(float x) {
  union { __bf16 b; unsigned short s; } u; u.b = (bf16_t)x; return u.s;
}
DEV f32x4 shfl_xor4(f32x4 v, int m) {
  f32x4 r;
  r[0] = __shfl_xor(v[0], m); r[1] = __shfl_xor(v[1], m);
  r[2] = __shfl_xor(v[2], m); r[3] = __shfl_xor(v[3], m);
  return r;
}

struct Params {
  const float* data;    // [32,512,240]
  const float* mask;    // [32,512]
  const float* wx_f; const float* wr_f; const float* bias_f; const float* wp_f;
  const float* wx_b; const float* wr_b; const float* bias_b; const float* wp_b;
  float* out;           // [32,512,1024]
  bf16_t* data_bf;      // [32,512,256] (K padded 240->256 with zeros)
  bf16_t* Wf;           // [4096,1280] packed fwd rows: [0,1024)=Wc, [1024,1280)=Wx
  bf16_t* Wb;           // [4096,768]  packed bwd rows: [0,512)=Wr, [512,768)=Wx
  bf16_t* wrf;          // [4096,512] bf16 copy of wr_f
  bf16_t* wpT;          // [1024,512] wp_f transposed
  bf16_t* wpf;          // [512,1024]
  bf16_t* wpb;          // [512,1024]
  float* bias_f_p;      // [4096] packed
  float* bias_b_p;      // [4096] packed
  bf16_t* h_hist;       // [512,32,1024]  fwd h history (sc1 write-through)
  bf16_t* h_buf;        // [512,1024]     bwd h (write-through)
  bf16_t* r_buf;        // [512,512]      bwd r (write-through)
  f32x4*  chb;          // [512,512] private (c0,h0,c1,h1) per unit-pair
  int* fcnt;            // [128 slots x 16 ints (64B)] monotonic, 1 writer each
  int* bcA;             // [128 slots x 16]
  int* bcC;             // [128 slots x 16]
};

// ---------------- sync helpers ----------------
DEV void poll_ge(int* p, int tgt) {
  while (__hip_atomic_load(p, __ATOMIC_RELAXED, __HIP_MEMORY_SCOPE_AGENT) < tgt)
    __builtin_amdgcn_s_sleep(1);
}
DEV void st_slot(int* p, int v) {
  __hip_atomic_store(p, v, __ATOMIC_RELAXED, __HIP_MEMORY_SCOPE_AGENT);
}
DEV void drain_sync() {
  asm volatile("s_waitcnt vmcnt(0)" ::: "memory");
  __syncthreads();
}

// ---------------- prep kernels ----------------
__global__ void k_data(Params P) {
  int idx = blockIdx.x * 256 + threadIdx.x;   // 32*512*256
  int k = idx & 255; int row = idx >> 8;
  float v = (k < 240) ? P.data[(size_t)row * 240 + k] : 0.0f;
  P.data_bf[idx] = (bf16_t)v;
}

__global__ void k_prep_w(Params P) {
  int idx = blockIdx.x * 256 + threadIdx.x;
  int n = 4096 * 512;
  if (idx < n) { P.wrf[idx] = (bf16_t)P.wr_f[idx]; return; }
  idx -= n; n = 1024 * 512;
  if (idx < n) { int h = idx >> 9, p = idx & 511;
                 P.wpT[idx] = (bf16_t)P.wp_f[(size_t)p * 1024 + h]; return; }
  idx -= n; n = 512 * 1024;
  if (idx < n) { P.wpf[idx] = (bf16_t)P.wp_f[idx]; return; }
  idx -= n; n = 512 * 1024;
  if (idx < n) { P.wpb[idx] = (bf16_t)P.wp_b[idx]; return; }
}

// fwd packed rows: pr = j*32 + nh*16 + u4*4 + g
//   <-> global gate row g*1024 + j*8 + nh*4 + u4
__global__ void k_packf(Params P) {
  int pr = blockIdx.x, k = threadIdx.x;     // k in [0,256)
  int j = pr >> 5, q = pr & 31, nh = q >> 4, u4 = (q >> 2) & 3, g = q & 3;
  int grow = g * 1024 + j * 8 + nh * 4 + u4;
  float v = (k < 240) ? P.wx_f[(size_t)grow * 240 + k] : 0.0f;
  P.Wf[(size_t)pr * 1280 + 1024 + k] = (bf16_t)v;
  if (k == 0) P.bias_f_p[pr] = P.bias_f[grow];
}

// bwd packed rows: pr = ut*256 + grp*64 + uu <-> global row grp*1024 + ut*64 + uu
__global__ void k_packb(Params P) {
  int pr = blockIdx.x; int k = blockIdx.y * 256 + threadIdx.x;  // k in [0,768)
  int ut = pr >> 8, rem = pr & 255, grp = rem >> 6, uu = rem & 63;
  int grow = grp * 1024 + ut * 64 + uu;
  float v;
  if (k < 512) v = P.wr_b[(size_t)grow * 512 + k];
  else { int kx = k - 512; v = (kx < 240) ? P.wx_b[(size_t)grow * 240 + kx] : 0.0f; }
  P.Wb[(size_t)pr * 768 + k] = (bf16_t)v;
  if (k == 0) P.bias_b_p[pr] = P.bias_b[grow];
}

// Wc = wr_f @ wp_f : [4096,1024], K=512; into packed Wf rows, cols [0,1024)
__global__ void wc_gemm(Params P) {
  int tid = threadIdx.x, lane = tid & 63, wave = tid >> 6;
  int lane15 = lane & 15, laneh = lane >> 4;
  int mt = blockIdx.x >> 4, nt = blockIdx.x & 15;
  f32x4 acc[4] = {};
  for (int kc = 0; kc < 16; ++kc) {
    int kl = kc * 32 + laneh * 8;
    bf16x8 bv = ldg8(P.wpT + (size_t)(nt * 64 + wave * 16 + lane15) * 512 + kl);
#pragma unroll
    for (int mh = 0; mh < 4; ++mh) {
      bf16x8 av = ldg8(P.wrf + (size_t)(mt * 64 + mh * 16 + lane15) * 512 + kl);
      acc[mh] = mfma16(av, bv, acc[mh]);
    }
  }
#pragma unroll
  for (int mh = 0; mh < 4; ++mh)
#pragma unroll
    for (int q = 0; q < 4; ++q) {
      int m = mt * 64 + mh * 16 + laneh * 4 + q;
      int grp = m >> 10, unit = m & 1023;
      int j = unit >> 3, rem = unit & 7, nh = rem >> 2, u4 = rem & 3;
      int pr = j * 32 + nh * 16 + u4 * 4 + grp;
      int ncol = nt * 64 + wave * 16 + lane15;
      P.Wf[(size_t)pr * 1280 + ncol] = (bf16_t)acc[mh][q];
    }
}

// ---------------- the scan kernel: blocks 0..127 fwd, 128..255 bwd ----------
__global__ void __launch_bounds__(256, 1) scan_kernel(Params P) {
  __shared__ float gates_sm[4][64][64];   // bwd only
  const int tid = threadIdx.x;
  const int lane = tid & 63, wave = tid >> 6;
  const int lane15 = lane & 15, laneh = lane >> 4;

  if (blockIdx.x < 128) {
    // ===== forward scan: block j owns units j*8..j*8+7; wave=(mh,nh) =======
    const int j = blockIdx.x;
    const int mh = wave & 1, nh = wave >> 1;
    const int col = lane15;              // = u4*4 + g
    const int g = col & 3, u4 = col >> 2;
    const bf16_t* Wfp = P.Wf + (size_t)(j * 32 + nh * 16 + col) * 1280;
    bf16x8 wb[40];
#pragma unroll
    for (int kc = 0; kc < 40; ++kc)
      wb[kc] = ldg8(Wfp + kc * 32 + laneh * 8);
    const float biasv = P.bias_f_p[j * 32 + nh * 16 + col];
    float c_st[4] = {0.f, 0.f, 0.f, 0.f}, h_st[4] = {0.f, 0.f, 0.f, 0.f};
    const int brow = mh * 16 + lane15;   // batch row for A-operand loads
    const int bq0 = mh * 16 + laneh * 4; // batch base for this lane's cells

    for (int t = 0; t < 512; ++t) {
      float mk[4];
#pragma unroll
      for (int q = 0; q < 4; ++q) mk[q] = P.mask[(bq0 + q) * 512 + t];
      f32x4 a0 = {biasv, biasv, biasv, biasv};
      f32x4 a1 = {}, a2 = {}, a3 = {};
      // ---- x-side GEMM (independent of h(t-1)) ----
      {
        const bf16_t* xrow = P.data_bf + ((size_t)brow * 512 + t) * 256 + laneh * 8;
        bf16x8 ax[8];
#pragma unroll
        for (int kk = 0; kk < 8; ++kk) ax[kk] = ldg8(xrow + kk * 32);
        a0 = mfma16(ax[0], wb[32], a0); a1 = mfma16(ax[1], wb[33], a1);
        a2 = mfma16(ax[2], wb[34], a2); a3 = mfma16(ax[3], wb[35], a3);
        a0 = mfma16(ax[4], wb[36], a0); a1 = mfma16(ax[5], wb[37], a1);
        a2 = mfma16(ax[6], wb[38], a2); a3 = mfma16(ax[7], wb[39], a3);
      }
      // ---- wait for h(t-1), then full-K h-GEMM (plain cached loads) ----
      if (t > 0) {
        if (tid < 128) poll_ge(P.fcnt + tid * 16, t);
        __syncthreads();
        asm volatile("" ::: "memory");
        const bf16_t* hrow = P.h_hist + (size_t)(t - 1) * 32768 +
                             (size_t)brow * 1024 + laneh * 8;
#pragma unroll
        for (int c8 = 0; c8 < 4; ++c8) {
          bf16x8 ah[8];
#pragma unroll
          for (int kk = 0; kk < 8; ++kk) ah[kk] = ldg8(hrow + c8 * 256 + kk * 32);
          a0 = mfma16(ah[0], wb[c8 * 8 + 0], a0);
          a1 = mfma16(ah[1], wb[c8 * 8 + 1], a1);
          a2 = mfma16(ah[2], wb[c8 * 8 + 2], a2);
          a3 = mfma16(ah[3], wb[c8 * 8 + 3], a3);
          a0 = mfma16(ah[4], wb[c8 * 8 + 4], a0);
          a1 = mfma16(ah[5], wb[c8 * 8 + 5], a1);
          a2 = mfma16(ah[6], wb[c8 * 8 + 6], a2);
          a3 = mfma16(ah[7], wb[c8 * 8 + 7], a3);
        }
      } else {
        __syncthreads();
      }
      f32x4 vacc = (a0 + a1) + (a2 + a3);
      // ---- gather the 4 gates across the col quad (12 shfls) ----
      f32x4 v1 = shfl_xor4(vacc, 1);
      f32x4 lo = (g & 1) ? v1 : vacc;
      f32x4 hi = (g & 1) ? vacc : v1;
      f32x4 lo2 = shfl_xor4(lo, 2);
      f32x4 hi2 = shfl_xor4(hi, 2);
      f32x4 gi_ = (g & 2) ? lo2 : lo;
      f32x4 gf_ = (g & 2) ? hi2 : hi;
      f32x4 gg_ = (g & 2) ? lo : lo2;
      f32x4 go_ = (g & 2) ? hi : hi2;
      // ---- cell updates: 4 batches x 1 unit per lane (x4 redundant) ----
      uint32 hb[4];
#pragma unroll
      for (int q = 0; q < 4; ++q) {
        float iv = sigmoidf_(gi_[q]);
        float fv = sigmoidf_(gf_[q]);
        float gv = tanhf_(gg_[q]);
        float ov = sigmoidf_(go_[q]);
        float cnew = fminf(1.0f, fmaxf(-1.0f, fv * c_st[q] + iv * gv));
        float hnew = ov * tanhf_(cnew);
        c_st[q] = mk[q] * cnew + (1.0f - mk[q]) * c_st[q];
        h_st[q] = mk[q] * hnew + (1.0f - mk[q]) * h_st[q];
        hb[q] = bfbits(h_st[q]);
      }
      // ---- pack 4 units into 8B granules across cols {0,4,8,12}; store ----
#pragma unroll
      for (int q = 0; q < 4; ++q) {
        uint32 a = hb[q];
        uint32 b1 = (uint32)__shfl_xor((int)a, 4);
        uint32 pp = (u4 & 1) ? (b1 | (a << 16)) : (a | (b1 << 16));
        uint32 c1 = (uint32)__shfl_xor((int)pp, 8);
        u64 gq = (u4 & 2) ? (((u64)pp << 32) | c1) : (((u64)c1 << 32) | pp);
        if (col == 0)
          st_a64((u64*)(P.h_hist + (size_t)t * 32768 +
                        (size_t)(bq0 + q) * 1024 + j * 8 + nh * 4), gq);
      }
      drain_sync();
      if (tid == 0) st_slot(&P.fcnt[j * 16], t + 1);
    }
  } else {
    // =============== backward scan (blocked, batch 512, 32 steps) ==========
    const int bx = blockIdx.x - 128;
    const int btA = bx >> 4, utA = bx & 15;   // phase A: [64 batch] x [64 units]
    const int btC = bx >> 3, ptC = bx & 7;    // phase C: [32 batch] x [64 p]
    const int un = tid & 31, nr = tid >> 5;   // phase-A consumer mapping
    float biasB[2][4];
#pragma unroll
    for (int e = 0; e < 2; ++e)
#pragma unroll
      for (int g2 = 0; g2 < 4; ++g2)
        biasB[e][g2] = P.bias_b_p[utA * 256 + g2 * 64 + 2 * un + e];

    for (int s = 0; s < 32; ++s) {
      // ---- phase A: gates + state update, writes h_buf (write-through) ----
      if (s > 0) {
        if (tid < 16) {
          int bxp = (btA * 2 + (tid >> 3)) * 8 + (tid & 7);
          poll_ge(P.bcC + bxp * 16, s);
        }
        __syncthreads();
        asm volatile("" ::: "memory");
      } else {
        __syncthreads();
      }
      f32x4 acc[4][4] = {};
      const bf16_t* WbBase = P.Wb + (size_t)(utA * 256 + wave * 64) * 768;
      for (int kc = 0; kc < 24; ++kc) {
        int kb = kc * 32;
        if (kb < 512 && s == 0) continue;    // r_{-1} = 0
        int kl = kb + laneh * 8;
        bf16x8 av[4];
        if (kb < 512) {
#pragma unroll
          for (int mh2 = 0; mh2 < 4; ++mh2)
            av[mh2] = ld_llc8(P.r_buf + (size_t)(btA * 64 + mh2 * 16 + lane15) * 512 + kl);
        } else {
          int kx = kl - 512;
#pragma unroll
          for (int mh2 = 0; mh2 < 4; ++mh2) {
            int n = btA * 64 + mh2 * 16 + lane15;
            int t2 = (n & 15) * 32 + 31 - s;
            av[mh2] = ldg8(P.data_bf + ((size_t)((n >> 4) * 512 + t2)) * 256 + kx);
          }
        }
#pragma unroll
        for (int nf = 0; nf < 4; ++nf) {
          bf16x8 bv = ldg8(WbBase + (size_t)(nf * 16 + lane15) * 768 + kl);
#pragma unroll
          for (int mh2 = 0; mh2 < 4; ++mh2)
            acc[mh2][nf] = mfma16(av[mh2], bv, acc[mh2][nf]);
        }
      }
#pragma unroll
      for (int mh2 = 0; mh2 < 4; ++mh2)
#pragma unroll
        for (int nf = 0; nf < 4; ++nf)
#pragma unroll
          for (int q = 0; q < 4; ++q)
            gates_sm[wave][mh2 * 16 + laneh * 4 + q][nf * 16 + lane15] = acc[mh2][nf][q];
      __syncthreads();

      for (int ii = 0; ii < 8; ++ii) {
        int n = ii * 8 + nr;
        int ng = btA * 64 + n;
        int b = ng >> 4;
        int t2 = (ng & 15) * 32 + 31 - s;
        float mk = P.mask[b * 512 + t2];
        size_t cix = (size_t)ng * 512 + utA * 32 + un;  // unit-pair index
        f32x4 chv;
        if (s == 0) { chv[0] = 0.f; chv[1] = 0.f; chv[2] = 0.f; chv[3] = 0.f; }
        else chv = P.chb[cix];
        uint32 pk = 0;
#pragma unroll
        for (int e = 0; e < 2; ++e) {
          float gi = gates_sm[0][n][2 * un + e] + biasB[e][0];
          float gf = gates_sm[1][n][2 * un + e] + biasB[e][1];
          float gg = gates_sm[2][n][2 * un + e] + biasB[e][2];
          float go = gates_sm[3][n][2 * un + e] + biasB[e][3];
          float iv = sigmoidf_(gi), fv = sigmoidf_(gf);
          float gv = tanhf_(gg), ov = sigmoidf_(go);
          float cold = chv[2 * e], hold = chv[2 * e + 1];
          float cnew = fminf(1.0f, fmaxf(-1.0f, fv * cold + iv * gv));
          float hnew = ov * tanhf_(cnew);
          float cm = mk * cnew + (1.0f - mk) * cold;
          float hm = mk * hnew + (1.0f - mk) * hold;
          chv[2 * e] = cm; chv[2 * e + 1] = hm;
          pk |= ((uint32)bfbits(hm)) << (16 * e);
        }
        P.chb[cix] = chv;
        st_llc_u32((uint32*)(P.h_buf + (size_t)ng * 1024 + utA * 64 + 2 * un), pk);
      }
      drain_sync();
      if (tid == 0) st_slot(&P.bcA[bx * 16], s + 1);

      // ---- phase C: r = h @ wp_b.T ; write d_out and r_buf ----
      if (tid < 16) poll_ge(P.bcA + ((btC >> 1) * 16 + tid) * 16, s + 1);
      __syncthreads();
      asm volatile("" ::: "memory");
      f32x4 acc2[2] = {};
      for (int kc = 0; kc < 32; ++kc) {
        int kl = kc * 32 + laneh * 8;
        bf16x8 bv = ldg8(P.wpb + (size_t)(ptC * 64 + wave * 16 + lane15) * 1024 + kl);
        bf16x8 q0 = ld_llc8(P.h_buf + (size_t)(btC * 32 + lane15) * 1024 + kl);
        bf16x8 q1 = ld_llc8(P.h_buf + (size_t)(btC * 32 + 16 + lane15) * 1024 + kl);
        acc2[0] = mfma16(q0, bv, acc2[0]);
        acc2[1] = mfma16(q1, bv, acc2[1]);
      }
#pragma unroll
      for (int mh2 = 0; mh2 < 2; ++mh2)
#pragma unroll
        for (int q = 0; q < 4; ++q) {
          int nl = mh2 * 16 + laneh * 4 + q;
          int ng = btC * 32 + nl;
          int b = ng >> 4;
          int t2 = (ng & 15) * 32 + 31 - s;
          int p = ptC * 64 + wave * 16 + lane15;
          float v = acc2[mh2][q];
          P.out[((size_t)b * 512 + t2) * 1024 + 512 + p] = v;
          float v2 = __shfl_xor(v, 1);
          if (!(lane & 1)) {
            uint32 pk = ((uint32)bfbits(v2) << 16) | bfbits(v);
            st_llc_u32((uint32*)(P.r_buf + (size_t)ng * 512 + p), pk);
          }
        }
      drain_sync();
      if (tid == 0) st_slot(&P.bcC[bx * 16], s + 1);
    }
  }
}

// out_f = h_hist @ wp_f.T : M=16384, N=512, K=1024
__global__ void fwd_proj(Params P) {
  int tid = threadIdx.x, lane = tid & 63, wave = tid >> 6;
  int lane15 = lane & 15, laneh = lane >> 4;
  int mt = blockIdx.x >> 3, nt = blockIdx.x & 7;
  f32x4 acc[4] = {};
  for (int kc = 0; kc < 32; ++kc) {
    int kl = kc * 32 + laneh * 8;
    bf16x8 bv = ldg8(P.wpf + (size_t)(nt * 64 + wave * 16 + lane15) * 1024 + kl);
#pragma unroll
    for (int mh = 0; mh < 4; ++mh) {
      bf16x8 av = ldg8(P.h_hist + (size_t)(mt * 64 + mh * 16 + lane15) * 1024 + kl);
      acc[mh] = mfma16(av, bv, acc[mh]);
    }
  }
#pragma unroll
  for (int mh = 0; mh < 4; ++mh)
#pragma unroll
    for (int q = 0; q < 4; ++q) {
      int m = mt * 64 + mh * 16 + laneh * 4 + q;
      int t = m >> 5, nb = m & 31;
      int p = nt * 64 + wave * 16 + lane15;
      P.out[((size_t)nb * 512 + t) * 1024 + p] = acc[mh][q];
    }
}

// ---------------------------------------------------------------------------
extern "C" void kernel_launch(void* const* d_in, const int* in_sizes, int n_in,
                              void* d_out, int out_size, void* d_ws, size_t ws_size,
                              hipStream_t stream) {
  (void)in_sizes; (void)n_in; (void)out_size; (void)ws_size;
  Params P;
  P.data   = (const float*)d_in[0];
  P.mask   = (const float*)d_in[1];
  P.wx_f   = (const float*)d_in[2];
  P.wr_f   = (const float*)d_in[3];
  P.bias_f = (const float*)d_in[4];
  P.wp_f   = (const float*)d_in[5];
  P.wx_b   = (const float*)d_in[6];
  P.wr_b   = (const float*)d_in[7];
  P.bias_b = (const float*)d_in[8];
  P.wp_b   = (const float*)d_in[9];
  P.out    = (float*)d_out;

  char* ws = (char*)d_ws;
  size_t o = 0;
  auto take = [&](size_t bytes) -> char* {
    char* p = ws + o; o += (bytes + 255) & ~(size_t)255; return p;
  };
  P.data_bf  = (bf16_t*)take(32ull * 512 * 256 * 2);
  P.Wf       = (bf16_t*)take(4096ull * 1280 * 2);
  P.Wb       = (bf16_t*)take(4096ull * 768 * 2);
  P.wrf      = (bf16_t*)take(4096ull * 512 * 2);
  P.wpT      = (bf16_t*)take(1024ull * 512 * 2);
  P.wpf      = (bf16_t*)take(512ull * 1024 * 2);
  P.wpb      = (bf16_t*)take(512ull * 1024 * 2);
  P.bias_f_p = (float*)take(4096 * 4);
  P.bias_b_p = (float*)take(4096 * 4);
  P.h_hist   = (bf16_t*)take(512ull * 32 * 1024 * 2);
  P.h_buf    = (bf16_t*)take(512ull * 1024 * 2);
  P.r_buf    = (bf16_t*)take(512ull * 512 * 2);
  P.chb      = (f32x4*)take(512ull * 512 * 16);
  size_t slot_i = 128ull * 16;
  char* cnts = take(3 * slot_i * 4);
  P.fcnt = (int*)cnts;
  P.bcA  = (int*)(cnts + slot_i * 4);
  P.bcC  = (int*)(cnts + 2 * slot_i * 4);

  hipMemsetAsync(cnts, 0, 3 * slot_i * 4, stream);
  k_data<<<16384, 256, 0, stream>>>(P);
  k_prep_w<<<14336, 256, 0, stream>>>(P);
  k_packf<<<4096, 256, 0, stream>>>(P);
  k_packb<<<dim3(4096, 3), 256, 0, stream>>>(P);
  wc_gemm<<<1024, 256, 0, stream>>>(P);
  scan_kernel<<<256, 256, 0, stream>>>(P);
  fwd_proj<<<2048, 256, 0, stream>>>(P);
}

// Round 8
// 2593.812 us; speedup vs baseline: 1.7694x; 1.6589x over previous
//
#include <hip/hip_runtime.h>
#include <hip/hip_bf16.h>
#include <math.h>

// ---------------------------------------------------------------------------
// UBLSTMP: bidirectional LSTM-with-projection.
//   fwd: T=512 sequential steps, batch 32, H=1024, P=512
//   bwd: 32 sequential steps over blocks of 32, batch 512, H=1024, P=512
// Round-8 = round-5 skeleton (best: 2.33ms scan) + three surgical changes:
//   1) per-HALF-block flags: waves 0/1 publish independently after draining
//      only their own sc1 h-stores (no block barrier+drain on publish path).
//   2) dependency-subset polling: consumer thread tid polls exactly ONE
//      producer half-flag (slot=tid); wave w thus waits only on its own 32
//      producer blocks (its K-slice), overlapping stragglers with compute.
//   3) mask prefetched at loop top (off the post-barrier critical path).
// Everything else (bwd scan, prep kernels, fwd_proj, Wc trick) identical.
// ---------------------------------------------------------------------------

typedef __bf16 bf16_t;
typedef __bf16 bf16x8 __attribute__((ext_vector_type(8)));
typedef float f32x4 __attribute__((ext_vector_type(4)));
typedef unsigned int uint32;
typedef unsigned long long u64;

#define DEV __device__ __forceinline__

DEV bf16x8 ldg8(const bf16_t* p) { return *reinterpret_cast<const bf16x8*>(p); }
DEV bf16x8 ld_llc8(const bf16_t* p) {
  union { bf16x8 v; u64 q[2]; } u;
  u64* pp = (u64*)p;
  u.q[0] = __hip_atomic_load(pp, __ATOMIC_RELAXED, __HIP_MEMORY_SCOPE_AGENT);
  u.q[1] = __hip_atomic_load(pp + 1, __ATOMIC_RELAXED, __HIP_MEMORY_SCOPE_AGENT);
  return u.v;
}
DEV void st_llc_u32(uint32* p, uint32 v) {
  __hip_atomic_store(p, v, __ATOMIC_RELAXED, __HIP_MEMORY_SCOPE_AGENT);
}
DEV f32x4 mfma16(bf16x8 a, bf16x8 b, f32x4 c) {
  return __builtin_amdgcn_mfma_f32_16x16x32_bf16(a, b, c, 0, 0, 0);
}
DEV float sigmoidf_(float x) { return 1.0f / (1.0f + __expf(-x)); }
DEV float tanhf_(float x) {  // fast tanh via e^{2x}
  float e = __expf(2.0f * x);
  return (e - 1.0f) / (e + 1.0f);
}
DEV unsigned short bfbits(float x) {
  union { __bf16 b; unsigned short s; } u; u.b = (bf16_t)x; return u.s;
}

struct Params {
  const float* data;    // [32,512,240]
  const float* mask;    // [32,512]
  const float* wx_f; const float* wr_f; const float* bias_f; const float* wp_f;
  const float* wx_b; const float* wr_b; const float* bias_b; const float* wp_b;
  float* out;           // [32,512,1024]
  bf16_t* data_bf;      // [32,512,256] (K padded 240->256 with zeros)
  bf16_t* Wf;           // [4096,1280] packed fwd rows: [0,1024)=Wc, [1024,1280)=Wx
  bf16_t* Wb;           // [4096,768]  packed bwd rows: [0,512)=Wr, [512,768)=Wx
  bf16_t* wrf;          // [4096,512] bf16 copy of wr_f
  bf16_t* wpT;          // [1024,512] wp_f transposed
  bf16_t* wpf;          // [512,1024]
  bf16_t* wpb;          // [512,1024]
  float* bias_f_p;      // [4096] packed
  float* bias_b_p;      // [4096] packed
  bf16_t* h_hist;       // [512,32,1024]  fwd h history (sc1 write-through)
  bf16_t* h_buf;        // [512,1024]     bwd h (write-through)
  bf16_t* r_buf;        // [512,512]      bwd r (write-through)
  f32x4*  chb;          // [512,512] private (c0,h0,c1,h1) per unit-pair
  int* fcnt;            // [256 half-flags x 16 ints (64B)]: slot j*2+wave
  int* bcA;             // [128 slots x 16]
  int* bcC;             // [128 slots x 16]
};

// ---------------- sync helpers ----------------
DEV void poll_ge(int* p, int tgt) {
  while (__hip_atomic_load(p, __ATOMIC_RELAXED, __HIP_MEMORY_SCOPE_AGENT) < tgt)
    __builtin_amdgcn_s_sleep(1);
}
DEV void st_slot(int* p, int v) {
  __hip_atomic_store(p, v, __ATOMIC_RELAXED, __HIP_MEMORY_SCOPE_AGENT);
}
DEV void drain_sync() {
  asm volatile("s_waitcnt vmcnt(0)" ::: "memory");
  __syncthreads();
}

// ---------------- prep kernels ----------------
__global__ void k_data(Params P) {
  int idx = blockIdx.x * 256 + threadIdx.x;   // 32*512*256
  int k = idx & 255; int row = idx >> 8;
  float v = (k < 240) ? P.data[(size_t)row * 240 + k] : 0.0f;
  P.data_bf[idx] = (bf16_t)v;
}

__global__ void k_prep_w(Params P) {
  int idx = blockIdx.x * 256 + threadIdx.x;
  int n = 4096 * 512;
  if (idx < n) { P.wrf[idx] = (bf16_t)P.wr_f[idx]; return; }
  idx -= n; n = 1024 * 512;
  if (idx < n) { int h = idx >> 9, p = idx & 511;
                 P.wpT[idx] = (bf16_t)P.wp_f[(size_t)p * 1024 + h]; return; }
  idx -= n; n = 512 * 1024;
  if (idx < n) { P.wpf[idx] = (bf16_t)P.wp_f[idx]; return; }
  idx -= n; n = 512 * 1024;
  if (idx < n) { P.wpb[idx] = (bf16_t)P.wp_b[idx]; return; }
}

// fwd packed rows: pr = j*32 + grp*8 + uu  <->  global gate row grp*1024 + j*8 + uu
__global__ void k_packf(Params P) {
  int pr = blockIdx.x, k = threadIdx.x;     // k in [0,256)
  int jj = pr >> 5, lr = pr & 31, grp = lr >> 3, uu = lr & 7;
  int grow = grp * 1024 + jj * 8 + uu;
  float v = (k < 240) ? P.wx_f[(size_t)grow * 240 + k] : 0.0f;
  P.Wf[(size_t)pr * 1280 + 1024 + k] = (bf16_t)v;
  if (k == 0) P.bias_f_p[pr] = P.bias_f[grow];
}

// bwd packed rows: pr = ut*256 + grp*64 + uu <-> global row grp*1024 + ut*64 + uu
__global__ void k_packb(Params P) {
  int pr = blockIdx.x; int k = blockIdx.y * 256 + threadIdx.x;  // k in [0,768)
  int ut = pr >> 8, rem = pr & 255, grp = rem >> 6, uu = rem & 63;
  int grow = grp * 1024 + ut * 64 + uu;
  float v;
  if (k < 512) v = P.wr_b[(size_t)grow * 512 + k];
  else { int kx = k - 512; v = (kx < 240) ? P.wx_b[(size_t)grow * 240 + kx] : 0.0f; }
  P.Wb[(size_t)pr * 768 + k] = (bf16_t)v;
  if (k == 0) P.bias_b_p[pr] = P.bias_b[grow];
}

// Wc = wr_f @ wp_f : [4096,1024], K=512; into packed Wf rows, cols [0,1024)
__global__ void wc_gemm(Params P) {
  int tid = threadIdx.x, lane = tid & 63, wave = tid >> 6;
  int lane15 = lane & 15, laneh = lane >> 4;
  int mt = blockIdx.x >> 4, nt = blockIdx.x & 15;
  f32x4 acc[4] = {};
  for (int kc = 0; kc < 16; ++kc) {
    int kl = kc * 32 + laneh * 8;
    bf16x8 bv = ldg8(P.wpT + (size_t)(nt * 64 + wave * 16 + lane15) * 512 + kl);
#pragma unroll
    for (int mh = 0; mh < 4; ++mh) {
      bf16x8 av = ldg8(P.wrf + (size_t)(mt * 64 + mh * 16 + lane15) * 512 + kl);
      acc[mh] = mfma16(av, bv, acc[mh]);
    }
  }
#pragma unroll
  for (int mh = 0; mh < 4; ++mh)
#pragma unroll
    for (int q = 0; q < 4; ++q) {
      int m = mt * 64 + mh * 16 + laneh * 4 + q;
      int grp = m >> 10, unit = m & 1023, jj = unit >> 3, u8 = unit & 7;
      int pr = jj * 32 + grp * 8 + u8;
      int ncol = nt * 64 + wave * 16 + lane15;
      P.Wf[(size_t)pr * 1280 + ncol] = (bf16_t)acc[mh][q];
    }
}

// ---------------- the scan kernel: blocks 0..127 fwd, 128..255 bwd ----------
__global__ void __launch_bounds__(256, 1) scan_kernel(Params P) {
  __shared__ union SM {
    float red[4][2][2][16][17];   // fwd: [wave][m][nh][m16][n16 pad]
    float gates[4][64][64];       // bwd: [group][n][uu]
  } sm;
  const int tid = threadIdx.x;
  const int lane = tid & 63, wave = tid >> 6;
  const int lane15 = lane & 15, laneh = lane >> 4;

  if (blockIdx.x < 128) {
    // =============== forward scan: block j owns hidden units j*8..j*8+7 ====
    const int j = blockIdx.x;
    const bf16_t* Wfp = P.Wf + (size_t)(j * 32) * 1280;
    // weights in VGPRs: wave w covers h-K [w*256,+256) and x-K [w*64,+64)
    bf16x8 wh[2][8], wx[2][2];
#pragma unroll
    for (int nh = 0; nh < 2; ++nh) {
#pragma unroll
      for (int kc = 0; kc < 8; ++kc)
        wh[nh][kc] = ldg8(Wfp + (size_t)(nh * 16 + lane15) * 1280 +
                          wave * 256 + kc * 32 + laneh * 8);
#pragma unroll
      for (int kc = 0; kc < 2; ++kc)
        wx[nh][kc] = ldg8(Wfp + (size_t)(nh * 16 + lane15) * 1280 +
                          1024 + wave * 64 + kc * 32 + laneh * 8);
    }
    const int cb = tid >> 2, up = tid & 3;   // consumer: (batch, unit-pair)
    float biasr[2][4];
    if (tid < 128) {
#pragma unroll
      for (int e = 0; e < 2; ++e)
#pragma unroll
        for (int g = 0; g < 4; ++g)
          biasr[e][g] = P.bias_f_p[j * 32 + g * 8 + 2 * up + e];
    }
    float c_st[2] = {0.f, 0.f}, h_st[2] = {0.f, 0.f};

    for (int t = 0; t < 512; ++t) {
      // ---- prefetch mask (off the post-barrier critical path) ----
      float mk = 0.0f;
      if (tid < 128) mk = P.mask[cb * 512 + t];
      // ---- x-side GEMM first (no dependence on previous step) ----
      f32x4 acc[2][2] = {};
      {
        bf16x8 ax[2][2];
#pragma unroll
        for (int kc = 0; kc < 2; ++kc) {
          int kx = wave * 64 + kc * 32 + laneh * 8;
          ax[0][kc] = ldg8(P.data_bf + ((size_t)(lane15 * 512 + t)) * 256 + kx);
          ax[1][kc] = ldg8(P.data_bf + ((size_t)((16 + lane15) * 512 + t)) * 256 + kx);
        }
#pragma unroll
        for (int kc = 0; kc < 2; ++kc)
#pragma unroll
          for (int m = 0; m < 2; ++m) {
            acc[m][0] = mfma16(ax[m][kc], wx[0][kc], acc[m][0]);
            acc[m][1] = mfma16(ax[m][kc], wx[1][kc], acc[m][1]);
          }
      }
      // ---- wait ONLY for this wave's 32 producer blocks (slot = tid) ----
      if (t > 0) {
        poll_ge(P.fcnt + tid * 16, t);
        asm volatile("" ::: "memory");
        const bf16_t* hrow = P.h_hist + (size_t)(t - 1) * 32768;
        bf16x8 ah[2][8];
#pragma unroll
        for (int kc = 0; kc < 8; ++kc) {
          int kl = wave * 256 + kc * 32 + laneh * 8;
          ah[0][kc] = ldg8(hrow + (size_t)lane15 * 1024 + kl);
          ah[1][kc] = ldg8(hrow + (size_t)(16 + lane15) * 1024 + kl);
        }
#pragma unroll
        for (int kc = 0; kc < 8; ++kc)
#pragma unroll
          for (int m = 0; m < 2; ++m) {
            acc[m][0] = mfma16(ah[m][kc], wh[0][kc], acc[m][0]);
            acc[m][1] = mfma16(ah[m][kc], wh[1][kc], acc[m][1]);
          }
      }
      // ---- cross-wave reduce via LDS (barrier 1: prev reads complete) ----
      __syncthreads();
#pragma unroll
      for (int m = 0; m < 2; ++m)
#pragma unroll
        for (int nh = 0; nh < 2; ++nh)
#pragma unroll
          for (int q = 0; q < 4; ++q)
            sm.red[wave][m][nh][laneh * 4 + q][lane15] = acc[m][nh][q];
      __syncthreads();   // barrier 2: writes visible to consumers

      // ---- consumer: 128 threads (waves 0,1), 2 cells each ----
      if (tid < 128) {
        uint32 pk = 0;
#pragma unroll
        for (int e = 0; e < 2; ++e) {
          float g4[4];
#pragma unroll
          for (int g = 0; g < 4; ++g) {
            int lr = g * 8 + 2 * up + e;
            float v = biasr[e][g];
#pragma unroll
            for (int w2 = 0; w2 < 4; ++w2)
              v += sm.red[w2][cb >> 4][lr >> 4][cb & 15][lr & 15];
            g4[g] = v;
          }
          float iv = sigmoidf_(g4[0]);
          float fv = sigmoidf_(g4[1]);
          float gv = tanhf_(g4[2]);
          float ov = sigmoidf_(g4[3]);
          float cnew = fminf(1.0f, fmaxf(-1.0f, fv * c_st[e] + iv * gv));
          float hnew = ov * tanhf_(cnew);
          c_st[e] = mk * cnew + (1.0f - mk) * c_st[e];
          h_st[e] = mk * hnew + (1.0f - mk) * h_st[e];
          pk |= ((uint32)bfbits(h_st[e])) << (16 * e);
        }
        st_llc_u32((uint32*)(P.h_hist + (size_t)t * 32768 + cb * 1024 + j * 8 + 2 * up), pk);
      }
      // ---- per-wave publish: drain own stores, set own half-flag ----
      if (wave < 2) {
        asm volatile("s_waitcnt vmcnt(0)" ::: "memory");
        if (lane == 0) st_slot(&P.fcnt[(j * 2 + wave) * 16], t + 1);
      }
      // no trailing barrier: barrier 1 of next iteration protects sm.red
    }
  } else {
    // =============== backward scan (blocked, batch 512, 32 steps) ==========
    const int bx = blockIdx.x - 128;
    const int btA = bx >> 4, utA = bx & 15;   // phase A: [64 batch] x [64 units]
    const int btC = bx >> 3, ptC = bx & 7;    // phase C: [32 batch] x [64 p]
    const int un = tid & 31, nr = tid >> 5;   // phase-A consumer mapping
    float biasB[2][4];
#pragma unroll
    for (int e = 0; e < 2; ++e)
#pragma unroll
      for (int g = 0; g < 4; ++g)
        biasB[e][g] = P.bias_b_p[utA * 256 + g * 64 + 2 * un + e];

    for (int s = 0; s < 32; ++s) {
      // ---- phase A: gates + state update, writes h_buf (write-through) ----
      if (s > 0) {
        if (tid < 16) {
          int bxp = (btA * 2 + (tid >> 3)) * 8 + (tid & 7);
          poll_ge(P.bcC + bxp * 16, s);
        }
        __syncthreads();
        asm volatile("" ::: "memory");
      } else {
        __syncthreads();
      }
      f32x4 acc[4][4] = {};
      const bf16_t* WbBase = P.Wb + (size_t)(utA * 256 + wave * 64) * 768;
      for (int kc = 0; kc < 24; ++kc) {
        int kb = kc * 32;
        if (kb < 512 && s == 0) continue;    // r_{-1} = 0
        int kl = kb + laneh * 8;
        bf16x8 av[4];
        if (kb < 512) {
#pragma unroll
          for (int mh = 0; mh < 4; ++mh)
            av[mh] = ld_llc8(P.r_buf + (size_t)(btA * 64 + mh * 16 + lane15) * 512 + kl);
        } else {
          int kx = kl - 512;
#pragma unroll
          for (int mh = 0; mh < 4; ++mh) {
            int n = btA * 64 + mh * 16 + lane15;
            int t2 = (n & 15) * 32 + 31 - s;
            av[mh] = ldg8(P.data_bf + ((size_t)((n >> 4) * 512 + t2)) * 256 + kx);
          }
        }
#pragma unroll
        for (int nf = 0; nf < 4; ++nf) {
          bf16x8 bv = ldg8(WbBase + (size_t)(nf * 16 + lane15) * 768 + kl);
#pragma unroll
          for (int mh = 0; mh < 4; ++mh)
            acc[mh][nf] = mfma16(av[mh], bv, acc[mh][nf]);
        }
      }
#pragma unroll
      for (int mh = 0; mh < 4; ++mh)
#pragma unroll
        for (int nf = 0; nf < 4; ++nf)
#pragma unroll
          for (int q = 0; q < 4; ++q)
            sm.gates[wave][mh * 16 + laneh * 4 + q][nf * 16 + lane15] = acc[mh][nf][q];
      __syncthreads();

      for (int ii = 0; ii < 8; ++ii) {
        int n = ii * 8 + nr;
        int ng = btA * 64 + n;
        int b = ng >> 4;
        int t2 = (ng & 15) * 32 + 31 - s;
        float mk = P.mask[b * 512 + t2];
        size_t cix = (size_t)ng * 512 + utA * 32 + un;  // unit-pair index
        f32x4 chv;
        if (s == 0) { chv[0] = 0.f; chv[1] = 0.f; chv[2] = 0.f; chv[3] = 0.f; }
        else chv = P.chb[cix];
        uint32 pk = 0;
#pragma unroll
        for (int e = 0; e < 2; ++e) {
          float gi = sm.gates[0][n][2 * un + e] + biasB[e][0];
          float gf = sm.gates[1][n][2 * un + e] + biasB[e][1];
          float gg = sm.gates[2][n][2 * un + e] + biasB[e][2];
          float go = sm.gates[3][n][2 * un + e] + biasB[e][3];
          float iv = sigmoidf_(gi), fv = sigmoidf_(gf);
          float gv = tanhf_(gg), ov = sigmoidf_(go);
          float cold = chv[2 * e], hold = chv[2 * e + 1];
          float cnew = fminf(1.0f, fmaxf(-1.0f, fv * cold + iv * gv));
          float hnew = ov * tanhf_(cnew);
          float cm = mk * cnew + (1.0f - mk) * cold;
          float hm = mk * hnew + (1.0f - mk) * hold;
          chv[2 * e] = cm; chv[2 * e + 1] = hm;
          pk |= ((uint32)bfbits(hm)) << (16 * e);
        }
        P.chb[cix] = chv;
        st_llc_u32((uint32*)(P.h_buf + (size_t)ng * 1024 + utA * 64 + 2 * un), pk);
      }
      drain_sync();
      if (tid == 0) st_slot(&P.bcA[bx * 16], s + 1);

      // ---- phase C: r = h @ wp_b.T ; write d_out and r_buf ----
      if (tid < 16) poll_ge(P.bcA + ((btC >> 1) * 16 + tid) * 16, s + 1);
      __syncthreads();
      asm volatile("" ::: "memory");
      f32x4 acc2[2] = {};
      for (int kc = 0; kc < 32; ++kc) {
        int kl = kc * 32 + laneh * 8;
        bf16x8 bv = ldg8(P.wpb + (size_t)(ptC * 64 + wave * 16 + lane15) * 1024 + kl);
        bf16x8 a0 = ld_llc8(P.h_buf + (size_t)(btC * 32 + lane15) * 1024 + kl);
        bf16x8 a1 = ld_llc8(P.h_buf + (size_t)(btC * 32 + 16 + lane15) * 1024 + kl);
        acc2[0] = mfma16(a0, bv, acc2[0]);
        acc2[1] = mfma16(a1, bv, acc2[1]);
      }
#pragma unroll
      for (int mh = 0; mh < 2; ++mh)
#pragma unroll
        for (int q = 0; q < 4; ++q) {
          int nl = mh * 16 + laneh * 4 + q;
          int ng = btC * 32 + nl;
          int b = ng >> 4;
          int t2 = (ng & 15) * 32 + 31 - s;
          int p = ptC * 64 + wave * 16 + lane15;
          float v = acc2[mh][q];
          P.out[((size_t)b * 512 + t2) * 1024 + 512 + p] = v;
          float v2 = __shfl_xor(v, 1);
          if (!(lane & 1)) {
            uint32 pk = ((uint32)bfbits(v2) << 16) | bfbits(v);
            st_llc_u32((uint32*)(P.r_buf + (size_t)ng * 512 + p), pk);
          }
        }
      drain_sync();
      if (tid == 0) st_slot(&P.bcC[bx * 16], s + 1);
    }
  }
}

// out_f = h_hist @ wp_f.T : M=16384, N=512, K=1024
__global__ void fwd_proj(Params P) {
  int tid = threadIdx.x, lane = tid & 63, wave = tid >> 6;
  int lane15 = lane & 15, laneh = lane >> 4;
  int mt = blockIdx.x >> 3, nt = blockIdx.x & 7;
  f32x4 acc[4] = {};
  for (int kc = 0; kc < 32; ++kc) {
    int kl = kc * 32 + laneh * 8;
    bf16x8 bv = ldg8(P.wpf + (size_t)(nt * 64 + wave * 16 + lane15) * 1024 + kl);
#pragma unroll
    for (int mh = 0; mh < 4; ++mh) {
      bf16x8 av = ldg8(P.h_hist + (size_t)(mt * 64 + mh * 16 + lane15) * 1024 + kl);
      acc[mh] = mfma16(av, bv, acc[mh]);
    }
  }
#pragma unroll
  for (int mh = 0; mh < 4; ++mh)
#pragma unroll
    for (int q = 0; q < 4; ++q) {
      int m = mt * 64 + mh * 16 + laneh * 4 + q;
      int t = m >> 5, nb = m & 31;
      int p = nt * 64 + wave * 16 + lane15;
      P.out[((size_t)nb * 512 + t) * 1024 + p] = acc[mh][q];
    }
}

// ---------------------------------------------------------------------------
extern "C" void kernel_launch(void* const* d_in, const int* in_sizes, int n_in,
                              void* d_out, int out_size, void* d_ws, size_t ws_size,
                              hipStream_t stream) {
  (void)in_sizes; (void)n_in; (void)out_size; (void)ws_size;
  Params P;
  P.data   = (const float*)d_in[0];
  P.mask   = (const float*)d_in[1];
  P.wx_f   = (const float*)d_in[2];
  P.wr_f   = (const float*)d_in[3];
  P.bias_f = (const float*)d_in[4];
  P.wp_f   = (const float*)d_in[5];
  P.wx_b   = (const float*)d_in[6];
  P.wr_b   = (const float*)d_in[7];
  P.bias_b = (const float*)d_in[8];
  P.wp_b   = (const float*)d_in[9];
  P.out    = (float*)d_out;

  char* ws = (char*)d_ws;
  size_t o = 0;
  auto take = [&](size_t bytes) -> char* {
    char* p = ws + o; o += (bytes + 255) & ~(size_t)255; return p;
  };
  P.data_bf  = (bf16_t*)take(32ull * 512 * 256 * 2);
  P.Wf       = (bf16_t*)take(4096ull * 1280 * 2);
  P.Wb       = (bf16_t*)take(4096ull * 768 * 2);
  P.wrf      = (bf16_t*)take(4096ull * 512 * 2);
  P.wpT      = (bf16_t*)take(1024ull * 512 * 2);
  P.wpf      = (bf16_t*)take(512ull * 1024 * 2);
  P.wpb      = (bf16_t*)take(512ull * 1024 * 2);
  P.bias_f_p = (float*)take(4096 * 4);
  P.bias_b_p = (float*)take(4096 * 4);
  P.h_hist   = (bf16_t*)take(512ull * 32 * 1024 * 2);
  P.h_buf    = (bf16_t*)take(512ull * 1024 * 2);
  P.r_buf    = (bf16_t*)take(512ull * 512 * 2);
  P.chb      = (f32x4*)take(512ull * 512 * 16);
  // flags: fcnt 256 half-block slots; bcA/bcC 128 slots; 64B spacing each
  size_t fcnt_i = 256ull * 16, bc_i = 128ull * 16;
  char* cnts = take((fcnt_i + 2 * bc_i) * 4);
  P.fcnt = (int*)cnts;
  P.bcA  = (int*)(cnts + fcnt_i * 4);
  P.bcC  = (int*)(cnts + (fcnt_i + bc_i) * 4);

  hipMemsetAsync(cnts, 0, (fcnt_i + 2 * bc_i) * 4, stream);
  k_data<<<16384, 256, 0, stream>>>(P);
  k_prep_w<<<14336, 256, 0, stream>>>(P);
  k_packf<<<4096, 256, 0, stream>>>(P);
  k_packb<<<dim3(4096, 3), 256, 0, stream>>>(P);
  wc_gemm<<<1024, 256, 0, stream>>>(P);
  scan_kernel<<<256, 256, 0, stream>>>(P);
  fwd_proj<<<2048, 256, 0, stream>>>(P);
}

// Round 9
// 2436.050 us; speedup vs baseline: 1.8840x; 1.0648x over previous
//
#include <hip/hip_runtime.h>
#include <hip/hip_bf16.h>
#include <math.h>

// ---------------------------------------------------------------------------
// UBLSTMP: bidirectional LSTM-with-projection.
//   fwd: T=512 sequential steps, batch 32, H=1024, P=512
//   bwd: 32 sequential steps over blocks of 32, batch 512, H=1024, P=512
// Round-9 = round-8 skeleton + three changes:
//   1) fwd loop reorder: x-loads issued, THEN poll (overlap detection with
//      x latency), THEN h-loads issued, THEN x-MFMAs (fill h latency),
//      THEN h-MFMAs. Pure code motion on the critical chain.
//   2) fwd_proj fused into the scan kernel: bwd blocks, after their 32-step
//      scan, grid-stride the 2048 out_f tiles, each gated on the fwd flags
//      (fcnt >= 2*mt+2). Separate fwd_proj dispatch removed.
//   3) +36KB dynamic LDS (total 100KB) forces 1 block/CU (no doubling-up
//      straggler).
// Sync protocol unchanged from r8: per-half-block monotonic flags, relaxed
// atomic publishes after per-wave vmcnt drain, wave-lockstep subset polling,
// sc1 write-through h stores, plain cached h loads (write-once addresses).
// ---------------------------------------------------------------------------

typedef __bf16 bf16_t;
typedef __bf16 bf16x8 __attribute__((ext_vector_type(8)));
typedef float f32x4 __attribute__((ext_vector_type(4)));
typedef unsigned int uint32;
typedef unsigned long long u64;

#define DEV __device__ __forceinline__

DEV bf16x8 ldg8(const bf16_t* p) { return *reinterpret_cast<const bf16x8*>(p); }
DEV bf16x8 ld_llc8(const bf16_t* p) {
  union { bf16x8 v; u64 q[2]; } u;
  u64* pp = (u64*)p;
  u.q[0] = __hip_atomic_load(pp, __ATOMIC_RELAXED, __HIP_MEMORY_SCOPE_AGENT);
  u.q[1] = __hip_atomic_load(pp + 1, __ATOMIC_RELAXED, __HIP_MEMORY_SCOPE_AGENT);
  return u.v;
}
DEV void st_llc_u32(uint32* p, uint32 v) {
  __hip_atomic_store(p, v, __ATOMIC_RELAXED, __HIP_MEMORY_SCOPE_AGENT);
}
DEV f32x4 mfma16(bf16x8 a, bf16x8 b, f32x4 c) {
  return __builtin_amdgcn_mfma_f32_16x16x32_bf16(a, b, c, 0, 0, 0);
}
DEV float sigmoidf_(float x) { return 1.0f / (1.0f + __expf(-x)); }
DEV float tanhf_(float x) {  // fast tanh via e^{2x}
  float e = __expf(2.0f * x);
  return (e - 1.0f) / (e + 1.0f);
}
DEV unsigned short bfbits(float x) {
  union { __bf16 b; unsigned short s; } u; u.b = (bf16_t)x; return u.s;
}

struct Params {
  const float* data;    // [32,512,240]
  const float* mask;    // [32,512]
  const float* wx_f; const float* wr_f; const float* bias_f; const float* wp_f;
  const float* wx_b; const float* wr_b; const float* bias_b; const float* wp_b;
  float* out;           // [32,512,1024]
  bf16_t* data_bf;      // [32,512,256] (K padded 240->256 with zeros)
  bf16_t* Wf;           // [4096,1280] packed fwd rows: [0,1024)=Wc, [1024,1280)=Wx
  bf16_t* Wb;           // [4096,768]  packed bwd rows: [0,512)=Wr, [512,768)=Wx
  bf16_t* wrf;          // [4096,512] bf16 copy of wr_f
  bf16_t* wpT;          // [1024,512] wp_f transposed
  bf16_t* wpf;          // [512,1024]
  bf16_t* wpb;          // [512,1024]
  float* bias_f_p;      // [4096] packed
  float* bias_b_p;      // [4096] packed
  bf16_t* h_hist;       // [512,32,1024]  fwd h history (sc1 write-through)
  bf16_t* h_buf;        // [512,1024]     bwd h (write-through)
  bf16_t* r_buf;        // [512,512]      bwd r (write-through)
  f32x4*  chb;          // [512,512] private (c0,h0,c1,h1) per unit-pair
  int* fcnt;            // [256 half-flags x 16 ints (64B)]: slot j*2+wave
  int* bcA;             // [128 slots x 16]
  int* bcC;             // [128 slots x 16]
};

// ---------------- sync helpers ----------------
DEV void poll_ge(int* p, int tgt) {
  while (__hip_atomic_load(p, __ATOMIC_RELAXED, __HIP_MEMORY_SCOPE_AGENT) < tgt)
    __builtin_amdgcn_s_sleep(1);
}
DEV void poll_ge_slow(int* p, int tgt) {   // coarse poll (off critical path)
  while (__hip_atomic_load(p, __ATOMIC_RELAXED, __HIP_MEMORY_SCOPE_AGENT) < tgt)
    __builtin_amdgcn_s_sleep(16);
}
DEV void st_slot(int* p, int v) {
  __hip_atomic_store(p, v, __ATOMIC_RELAXED, __HIP_MEMORY_SCOPE_AGENT);
}
DEV void drain_sync() {
  asm volatile("s_waitcnt vmcnt(0)" ::: "memory");
  __syncthreads();
}

// ---------------- prep kernels ----------------
__global__ void k_data(Params P) {
  int idx = blockIdx.x * 256 + threadIdx.x;   // 32*512*256
  int k = idx & 255; int row = idx >> 8;
  float v = (k < 240) ? P.data[(size_t)row * 240 + k] : 0.0f;
  P.data_bf[idx] = (bf16_t)v;
}

__global__ void k_prep_w(Params P) {
  int idx = blockIdx.x * 256 + threadIdx.x;
  int n = 4096 * 512;
  if (idx < n) { P.wrf[idx] = (bf16_t)P.wr_f[idx]; return; }
  idx -= n; n = 1024 * 512;
  if (idx < n) { int h = idx >> 9, p = idx & 511;
                 P.wpT[idx] = (bf16_t)P.wp_f[(size_t)p * 1024 + h]; return; }
  idx -= n; n = 512 * 1024;
  if (idx < n) { P.wpf[idx] = (bf16_t)P.wp_f[idx]; return; }
  idx -= n; n = 512 * 1024;
  if (idx < n) { P.wpb[idx] = (bf16_t)P.wp_b[idx]; return; }
}

// fwd packed rows: pr = j*32 + grp*8 + uu  <->  global gate row grp*1024 + j*8 + uu
__global__ void k_packf(Params P) {
  int pr = blockIdx.x, k = threadIdx.x;     // k in [0,256)
  int jj = pr >> 5, lr = pr & 31, grp = lr >> 3, uu = lr & 7;
  int grow = grp * 1024 + jj * 8 + uu;
  float v = (k < 240) ? P.wx_f[(size_t)grow * 240 + k] : 0.0f;
  P.Wf[(size_t)pr * 1280 + 1024 + k] = (bf16_t)v;
  if (k == 0) P.bias_f_p[pr] = P.bias_f[grow];
}

// bwd packed rows: pr = ut*256 + grp*64 + uu <-> global row grp*1024 + ut*64 + uu
__global__ void k_packb(Params P) {
  int pr = blockIdx.x; int k = blockIdx.y * 256 + threadIdx.x;  // k in [0,768)
  int ut = pr >> 8, rem = pr & 255, grp = rem >> 6, uu = rem & 63;
  int grow = grp * 1024 + ut * 64 + uu;
  float v;
  if (k < 512) v = P.wr_b[(size_t)grow * 512 + k];
  else { int kx = k - 512; v = (kx < 240) ? P.wx_b[(size_t)grow * 240 + kx] : 0.0f; }
  P.Wb[(size_t)pr * 768 + k] = (bf16_t)v;
  if (k == 0) P.bias_b_p[pr] = P.bias_b[grow];
}

// Wc = wr_f @ wp_f : [4096,1024], K=512; into packed Wf rows, cols [0,1024)
__global__ void wc_gemm(Params P) {
  int tid = threadIdx.x, lane = tid & 63, wave = tid >> 6;
  int lane15 = lane & 15, laneh = lane >> 4;
  int mt = blockIdx.x >> 4, nt = blockIdx.x & 15;
  f32x4 acc[4] = {};
  for (int kc = 0; kc < 16; ++kc) {
    int kl = kc * 32 + laneh * 8;
    bf16x8 bv = ldg8(P.wpT + (size_t)(nt * 64 + wave * 16 + lane15) * 512 + kl);
#pragma unroll
    for (int mh = 0; mh < 4; ++mh) {
      bf16x8 av = ldg8(P.wrf + (size_t)(mt * 64 + mh * 16 + lane15) * 512 + kl);
      acc[mh] = mfma16(av, bv, acc[mh]);
    }
  }
#pragma unroll
  for (int mh = 0; mh < 4; ++mh)
#pragma unroll
    for (int q = 0; q < 4; ++q) {
      int m = mt * 64 + mh * 16 + laneh * 4 + q;
      int grp = m >> 10, unit = m & 1023, jj = unit >> 3, u8 = unit & 7;
      int pr = jj * 32 + grp * 8 + u8;
      int ncol = nt * 64 + wave * 16 + lane15;
      P.Wf[(size_t)pr * 1280 + ncol] = (bf16_t)acc[mh][q];
    }
}

// ---------------- the scan kernel: blocks 0..127 fwd, 128..255 bwd+proj -----
__global__ void __launch_bounds__(256, 1) scan_kernel(Params P) {
  extern __shared__ char dyn_pad_[];   // occupancy limiter (1 block/CU)
  (void)dyn_pad_;
  __shared__ union SM {
    float red[4][2][2][16][17];   // fwd: [wave][m][nh][m16][n16 pad]
    float gates[4][64][64];       // bwd: [group][n][uu]
  } sm;
  const int tid = threadIdx.x;
  const int lane = tid & 63, wave = tid >> 6;
  const int lane15 = lane & 15, laneh = lane >> 4;

  if (blockIdx.x < 128) {
    // =============== forward scan: block j owns hidden units j*8..j*8+7 ====
    const int j = blockIdx.x;
    const bf16_t* Wfp = P.Wf + (size_t)(j * 32) * 1280;
    // weights in VGPRs: wave w covers h-K [w*256,+256) and x-K [w*64,+64)
    bf16x8 wh[2][8], wx[2][2];
#pragma unroll
    for (int nh = 0; nh < 2; ++nh) {
#pragma unroll
      for (int kc = 0; kc < 8; ++kc)
        wh[nh][kc] = ldg8(Wfp + (size_t)(nh * 16 + lane15) * 1280 +
                          wave * 256 + kc * 32 + laneh * 8);
#pragma unroll
      for (int kc = 0; kc < 2; ++kc)
        wx[nh][kc] = ldg8(Wfp + (size_t)(nh * 16 + lane15) * 1280 +
                          1024 + wave * 64 + kc * 32 + laneh * 8);
    }
    const int cb = tid >> 2, up = tid & 3;   // consumer: (batch, unit-pair)
    float biasr[2][4];
    if (tid < 128) {
#pragma unroll
      for (int e = 0; e < 2; ++e)
#pragma unroll
        for (int g = 0; g < 4; ++g)
          biasr[e][g] = P.bias_f_p[j * 32 + g * 8 + 2 * up + e];
    }
    float c_st[2] = {0.f, 0.f}, h_st[2] = {0.f, 0.f};

    for (int t = 0; t < 512; ++t) {
      // ---- prefetch mask ----
      float mk = 0.0f;
      if (tid < 128) mk = P.mask[cb * 512 + t];
      // ---- issue x loads (no dependence on previous step) ----
      bf16x8 ax0[2], ax1[2];
#pragma unroll
      for (int kc = 0; kc < 2; ++kc) {
        int kx = wave * 64 + kc * 32 + laneh * 8;
        ax0[kc] = ldg8(P.data_bf + ((size_t)(lane15 * 512 + t)) * 256 + kx);
        ax1[kc] = ldg8(P.data_bf + ((size_t)((16 + lane15) * 512 + t)) * 256 + kx);
      }
      f32x4 acc[2][2] = {};
      if (t > 0) {
        // ---- poll FIRST (detection overlaps x-load latency); wave-lockstep
        //      per-lane subset poll covers exactly this wave's 32 producers
        poll_ge(P.fcnt + tid * 16, t);
        asm volatile("" ::: "memory");
        // ---- issue h loads ----
        const bf16_t* hrow = P.h_hist + (size_t)(t - 1) * 32768;
        bf16x8 ah[2][8];
#pragma unroll
        for (int kc = 0; kc < 8; ++kc) {
          int kl = wave * 256 + kc * 32 + laneh * 8;
          ah[0][kc] = ldg8(hrow + (size_t)lane15 * 1024 + kl);
          ah[1][kc] = ldg8(hrow + (size_t)(16 + lane15) * 1024 + kl);
        }
        // ---- x MFMAs fill the h-load latency ----
#pragma unroll
        for (int kc = 0; kc < 2; ++kc) {
          acc[0][0] = mfma16(ax0[kc], wx[0][kc], acc[0][0]);
          acc[0][1] = mfma16(ax0[kc], wx[1][kc], acc[0][1]);
          acc[1][0] = mfma16(ax1[kc], wx[0][kc], acc[1][0]);
          acc[1][1] = mfma16(ax1[kc], wx[1][kc], acc[1][1]);
        }
        // ---- h MFMAs ----
#pragma unroll
        for (int kc = 0; kc < 8; ++kc)
#pragma unroll
          for (int m = 0; m < 2; ++m) {
            acc[m][0] = mfma16(ah[m][kc], wh[0][kc], acc[m][0]);
            acc[m][1] = mfma16(ah[m][kc], wh[1][kc], acc[m][1]);
          }
      } else {
#pragma unroll
        for (int kc = 0; kc < 2; ++kc) {
          acc[0][0] = mfma16(ax0[kc], wx[0][kc], acc[0][0]);
          acc[0][1] = mfma16(ax0[kc], wx[1][kc], acc[0][1]);
          acc[1][0] = mfma16(ax1[kc], wx[0][kc], acc[1][0]);
          acc[1][1] = mfma16(ax1[kc], wx[1][kc], acc[1][1]);
        }
      }
      // ---- cross-wave reduce via LDS (barrier 1: prev reads complete) ----
      __syncthreads();
#pragma unroll
      for (int m = 0; m < 2; ++m)
#pragma unroll
        for (int nh = 0; nh < 2; ++nh)
#pragma unroll
          for (int q = 0; q < 4; ++q)
            sm.red[wave][m][nh][laneh * 4 + q][lane15] = acc[m][nh][q];
      __syncthreads();   // barrier 2: writes visible to consumers

      // ---- consumer: 128 threads (waves 0,1), 2 cells each ----
      if (tid < 128) {
        uint32 pk = 0;
#pragma unroll
        for (int e = 0; e < 2; ++e) {
          float g4[4];
#pragma unroll
          for (int g = 0; g < 4; ++g) {
            int lr = g * 8 + 2 * up + e;
            float v = biasr[e][g];
#pragma unroll
            for (int w2 = 0; w2 < 4; ++w2)
              v += sm.red[w2][cb >> 4][lr >> 4][cb & 15][lr & 15];
            g4[g] = v;
          }
          float iv = sigmoidf_(g4[0]);
          float fv = sigmoidf_(g4[1]);
          float gv = tanhf_(g4[2]);
          float ov = sigmoidf_(g4[3]);
          float cnew = fminf(1.0f, fmaxf(-1.0f, fv * c_st[e] + iv * gv));
          float hnew = ov * tanhf_(cnew);
          c_st[e] = mk * cnew + (1.0f - mk) * c_st[e];
          h_st[e] = mk * hnew + (1.0f - mk) * h_st[e];
          pk |= ((uint32)bfbits(h_st[e])) << (16 * e);
        }
        st_llc_u32((uint32*)(P.h_hist + (size_t)t * 32768 + cb * 1024 + j * 8 + 2 * up), pk);
      }
      // ---- per-wave publish: drain own stores, set own half-flag ----
      if (wave < 2) {
        asm volatile("s_waitcnt vmcnt(0)" ::: "memory");
        if (lane == 0) st_slot(&P.fcnt[(j * 2 + wave) * 16], t + 1);
      }
      // no trailing barrier: barrier 1 of next iteration protects sm.red
    }
  } else {
    // =============== backward scan (blocked, batch 512, 32 steps) ==========
    const int bx = blockIdx.x - 128;
    const int btA = bx >> 4, utA = bx & 15;   // phase A: [64 batch] x [64 units]
    const int btC = bx >> 3, ptC = bx & 7;    // phase C: [32 batch] x [64 p]
    const int un = tid & 31, nr = tid >> 5;   // phase-A consumer mapping
    float biasB[2][4];
#pragma unroll
    for (int e = 0; e < 2; ++e)
#pragma unroll
      for (int g = 0; g < 4; ++g)
        biasB[e][g] = P.bias_b_p[utA * 256 + g * 64 + 2 * un + e];

    for (int s = 0; s < 32; ++s) {
      // ---- phase A: gates + state update, writes h_buf (write-through) ----
      if (s > 0) {
        if (tid < 16) {
          int bxp = (btA * 2 + (tid >> 3)) * 8 + (tid & 7);
          poll_ge(P.bcC + bxp * 16, s);
        }
        __syncthreads();
        asm volatile("" ::: "memory");
      } else {
        __syncthreads();
      }
      f32x4 acc[4][4] = {};
      const bf16_t* WbBase = P.Wb + (size_t)(utA * 256 + wave * 64) * 768;
      for (int kc = 0; kc < 24; ++kc) {
        int kb = kc * 32;
        if (kb < 512 && s == 0) continue;    // r_{-1} = 0
        int kl = kb + laneh * 8;
        bf16x8 av[4];
        if (kb < 512) {
#pragma unroll
          for (int mh = 0; mh < 4; ++mh)
            av[mh] = ld_llc8(P.r_buf + (size_t)(btA * 64 + mh * 16 + lane15) * 512 + kl);
        } else {
          int kx = kl - 512;
#pragma unroll
          for (int mh = 0; mh < 4; ++mh) {
            int n = btA * 64 + mh * 16 + lane15;
            int t2 = (n & 15) * 32 + 31 - s;
            av[mh] = ldg8(P.data_bf + ((size_t)((n >> 4) * 512 + t2)) * 256 + kx);
          }
        }
#pragma unroll
        for (int nf = 0; nf < 4; ++nf) {
          bf16x8 bv = ldg8(WbBase + (size_t)(nf * 16 + lane15) * 768 + kl);
#pragma unroll
          for (int mh = 0; mh < 4; ++mh)
            acc[mh][nf] = mfma16(av[mh], bv, acc[mh][nf]);
        }
      }
#pragma unroll
      for (int mh = 0; mh < 4; ++mh)
#pragma unroll
        for (int nf = 0; nf < 4; ++nf)
#pragma unroll
          for (int q = 0; q < 4; ++q)
            sm.gates[wave][mh * 16 + laneh * 4 + q][nf * 16 + lane15] = acc[mh][nf][q];
      __syncthreads();

      for (int ii = 0; ii < 8; ++ii) {
        int n = ii * 8 + nr;
        int ng = btA * 64 + n;
        int b = ng >> 4;
        int t2 = (ng & 15) * 32 + 31 - s;
        float mk = P.mask[b * 512 + t2];
        size_t cix = (size_t)ng * 512 + utA * 32 + un;  // unit-pair index
        f32x4 chv;
        if (s == 0) { chv[0] = 0.f; chv[1] = 0.f; chv[2] = 0.f; chv[3] = 0.f; }
        else chv = P.chb[cix];
        uint32 pk = 0;
#pragma unroll
        for (int e = 0; e < 2; ++e) {
          float gi = sm.gates[0][n][2 * un + e] + biasB[e][0];
          float gf = sm.gates[1][n][2 * un + e] + biasB[e][1];
          float gg = sm.gates[2][n][2 * un + e] + biasB[e][2];
          float go = sm.gates[3][n][2 * un + e] + biasB[e][3];
          float iv = sigmoidf_(gi), fv = sigmoidf_(gf);
          float gv = tanhf_(gg), ov = sigmoidf_(go);
          float cold = chv[2 * e], hold = chv[2 * e + 1];
          float cnew = fminf(1.0f, fmaxf(-1.0f, fv * cold + iv * gv));
          float hnew = ov * tanhf_(cnew);
          float cm = mk * cnew + (1.0f - mk) * cold;
          float hm = mk * hnew + (1.0f - mk) * hold;
          chv[2 * e] = cm; chv[2 * e + 1] = hm;
          pk |= ((uint32)bfbits(hm)) << (16 * e);
        }
        P.chb[cix] = chv;
        st_llc_u32((uint32*)(P.h_buf + (size_t)ng * 1024 + utA * 64 + 2 * un), pk);
      }
      drain_sync();
      if (tid == 0) st_slot(&P.bcA[bx * 16], s + 1);

      // ---- phase C: r = h @ wp_b.T ; write d_out and r_buf ----
      if (tid < 16) poll_ge(P.bcA + ((btC >> 1) * 16 + tid) * 16, s + 1);
      __syncthreads();
      asm volatile("" ::: "memory");
      f32x4 acc2[2] = {};
      for (int kc = 0; kc < 32; ++kc) {
        int kl = kc * 32 + laneh * 8;
        bf16x8 bv = ldg8(P.wpb + (size_t)(ptC * 64 + wave * 16 + lane15) * 1024 + kl);
        bf16x8 a0 = ld_llc8(P.h_buf + (size_t)(btC * 32 + lane15) * 1024 + kl);
        bf16x8 a1 = ld_llc8(P.h_buf + (size_t)(btC * 32 + 16 + lane15) * 1024 + kl);
        acc2[0] = mfma16(a0, bv, acc2[0]);
        acc2[1] = mfma16(a1, bv, acc2[1]);
      }
#pragma unroll
      for (int mh = 0; mh < 2; ++mh)
#pragma unroll
        for (int q = 0; q < 4; ++q) {
          int nl = mh * 16 + laneh * 4 + q;
          int ng = btC * 32 + nl;
          int b = ng >> 4;
          int t2 = (ng & 15) * 32 + 31 - s;
          int p = ptC * 64 + wave * 16 + lane15;
          float v = acc2[mh][q];
          P.out[((size_t)b * 512 + t2) * 1024 + 512 + p] = v;
          float v2 = __shfl_xor(v, 1);
          if (!(lane & 1)) {
            uint32 pk = ((uint32)bfbits(v2) << 16) | bfbits(v);
            st_llc_u32((uint32*)(P.r_buf + (size_t)ng * 512 + p), pk);
          }
        }
      drain_sync();
      if (tid == 0) st_slot(&P.bcC[bx * 16], s + 1);
    }

    // ========== fused out_f projection: h_hist @ wp_f.T, flag-gated =========
    // 2048 tiles of [64m x 64n]; M = t*32 + batch. Tile mt needs fwd steps
    // [0, 2*mt+2) complete: poll all 256 half-flags (wave-lockstep covers 64
    // each, barrier joins the 4 waves). h_hist is write-once => plain cached
    // loads are coherent, and any L2 fill happens post-flag.
    for (int tile = bx; tile < 2048; tile += 128) {
      int mt = tile >> 3, nt = tile & 7;
      poll_ge_slow(P.fcnt + tid * 16, 2 * mt + 2);
      __syncthreads();
      asm volatile("" ::: "memory");
      f32x4 acc[4] = {};
      for (int kc = 0; kc < 32; ++kc) {
        int kl = kc * 32 + laneh * 8;
        bf16x8 bv = ldg8(P.wpf + (size_t)(nt * 64 + wave * 16 + lane15) * 1024 + kl);
#pragma unroll
        for (int mh = 0; mh < 4; ++mh) {
          bf16x8 av = ldg8(P.h_hist + (size_t)(mt * 64 + mh * 16 + lane15) * 1024 + kl);
          acc[mh] = mfma16(av, bv, acc[mh]);
        }
      }
#pragma unroll
      for (int mh = 0; mh < 4; ++mh)
#pragma unroll
        for (int q = 0; q < 4; ++q) {
          int m = mt * 64 + mh * 16 + laneh * 4 + q;
          int t = m >> 5, nb = m & 31;
          int p = nt * 64 + wave * 16 + lane15;
          P.out[((size_t)nb * 512 + t) * 1024 + p] = acc[mh][q];
        }
      __syncthreads();   // all waves done before next tile's poll reuses slots
    }
  }
}

// ---------------------------------------------------------------------------
extern "C" void kernel_launch(void* const* d_in, const int* in_sizes, int n_in,
                              void* d_out, int out_size, void* d_ws, size_t ws_size,
                              hipStream_t stream) {
  (void)in_sizes; (void)n_in; (void)out_size; (void)ws_size;
  Params P;
  P.data   = (const float*)d_in[0];
  P.mask   = (const float*)d_in[1];
  P.wx_f   = (const float*)d_in[2];
  P.wr_f   = (const float*)d_in[3];
  P.bias_f = (const float*)d_in[4];
  P.wp_f   = (const float*)d_in[5];
  P.wx_b   = (const float*)d_in[6];
  P.wr_b   = (const float*)d_in[7];
  P.bias_b = (const float*)d_in[8];
  P.wp_b   = (const float*)d_in[9];
  P.out    = (float*)d_out;

  char* ws = (char*)d_ws;
  size_t o = 0;
  auto take = [&](size_t bytes) -> char* {
    char* p = ws + o; o += (bytes + 255) & ~(size_t)255; return p;
  };
  P.data_bf  = (bf16_t*)take(32ull * 512 * 256 * 2);
  P.Wf       = (bf16_t*)take(4096ull * 1280 * 2);
  P.Wb       = (bf16_t*)take(4096ull * 768 * 2);
  P.wrf      = (bf16_t*)take(4096ull * 512 * 2);
  P.wpT      = (bf16_t*)take(1024ull * 512 * 2);
  P.wpf      = (bf16_t*)take(512ull * 1024 * 2);
  P.wpb      = (bf16_t*)take(512ull * 1024 * 2);
  P.bias_f_p = (float*)take(4096 * 4);
  P.bias_b_p = (float*)take(4096 * 4);
  P.h_hist   = (bf16_t*)take(512ull * 32 * 1024 * 2);
  P.h_buf    = (bf16_t*)take(512ull * 1024 * 2);
  P.r_buf    = (bf16_t*)take(512ull * 512 * 2);
  P.chb      = (f32x4*)take(512ull * 512 * 16);
  // flags: fcnt 256 half-block slots; bcA/bcC 128 slots; 64B spacing each
  size_t fcnt_i = 256ull * 16, bc_i = 128ull * 16;
  char* cnts = take((fcnt_i + 2 * bc_i) * 4);
  P.fcnt = (int*)cnts;
  P.bcA  = (int*)(cnts + fcnt_i * 4);
  P.bcC  = (int*)(cnts + (fcnt_i + bc_i) * 4);

  hipMemsetAsync(cnts, 0, (fcnt_i + 2 * bc_i) * 4, stream);
  k_data<<<16384, 256, 0, stream>>>(P);
  k_prep_w<<<14336, 256, 0, stream>>>(P);
  k_packf<<<4096, 256, 0, stream>>>(P);
  k_packb<<<dim3(4096, 3), 256, 0, stream>>>(P);
  wc_gemm<<<1024, 256, 0, stream>>>(P);
  scan_kernel<<<256, 256, 36864, stream>>>(P);   // +36KB dyn LDS: 1 block/CU
}